// Round 14
// baseline (196.339 us; speedup 1.0000x reference)
//
#include <hip/hip_runtime.h>
#include <hip/hip_bf16.h>

typedef unsigned short u16;
typedef unsigned int u32;
typedef __attribute__((ext_vector_type(8))) short bf16x8;
typedef __attribute__((ext_vector_type(4))) float f32x4;

#define S_LEN 4096
#define DHEAD 128
#define NHEAD 8
#define NBATCH 2

__device__ __forceinline__ u16 f2b(float f) {
  __hip_bfloat16 h = __float2bfloat16(f);
  return *(u16*)&h;
}

__device__ __forceinline__ f32x4 mfma16(bf16x8 a, bf16x8 b, f32x4 c) {
  return __builtin_amdgcn_mfma_f32_16x16x32_bf16(a, b, c, 0, 0, 0);
}

__device__ __forceinline__ f32x4 zero4() { f32x4 z = {0.f, 0.f, 0.f, 0.f}; return z; }

// async global->LDS, 16B per lane; LDS dest = wave-uniform base + lane*16
__device__ __forceinline__ void gll16(const u16* g, u16* l) {
  __builtin_amdgcn_global_load_lds(
      (const __attribute__((address_space(1))) u32*)g,
      (__attribute__((address_space(3))) u32*)l, 16, 0, 0);
}

// ---------------- converts ----------------
__global__ void k_conv_x(const float* __restrict__ x, u16* __restrict__ xb,
                         u16* __restrict__ xT) {
  int idx = blockIdx.x * blockDim.x + threadIdx.x;
  float v = x[idx];
  u16 bv = f2b(v);
  xb[idx] = bv;
  int d = idx & 127;
  int bs = idx >> 7;
  int b = bs >> 12;
  int s = bs & 4095;
  xT[((size_t)b * DHEAD + d) * S_LEN + s] = bv;
}

__global__ void k_conv_w(const float* __restrict__ Wq, const float* __restrict__ Wk,
                         const float* __restrict__ Wo, u16* __restrict__ Wqt,
                         u16* __restrict__ Wkt, u16* __restrict__ WoB) {
  int idx = blockIdx.x * blockDim.x + threadIdx.x;
  int h = idx >> 14;
  int d = (idx >> 7) & 127;
  int e = idx & 127;
  int t = (h << 14) + (e << 7) + d;
  Wqt[t] = f2b(Wq[idx]);
  Wkt[t] = f2b(Wk[idx]);
  WoB[idx] = f2b(Wo[idx]);
}

// ---------------- Q/K projection: 4 waves/block ----------------
__global__ __launch_bounds__(256) void k_proj(const u16* __restrict__ xb,
                                              const u16* __restrict__ Wqt,
                                              const u16* __restrict__ Wkt,
                                              u16* __restrict__ Qb, u16* __restrict__ Kb) {
  int wid = threadIdx.x >> 6;
  int lane = threadIdx.x & 63;
  int qt = blockIdx.x * 4 + wid;
  int h = blockIdx.y, z = blockIdx.z;
  int b = z >> 1, w = z & 1;
  int row16 = lane & 15, kgrp = lane >> 4;
  int sb = qt * 32;
  const u16* xp = xb + ((size_t)b * S_LEN + sb) * DHEAD;
  bf16x8 a[2][4];
#pragma unroll
  for (int r = 0; r < 2; ++r)
#pragma unroll
    for (int kc = 0; kc < 4; ++kc)
      a[r][kc] = *(const bf16x8*)(xp + (r * 16 + row16) * DHEAD + kc * 32 + kgrp * 8);

  const u16* Wt = (w == 0 ? Wqt : Wkt) + (size_t)h * DHEAD * DHEAD;
  u16* Out = (w == 0 ? Qb : Kb) + ((size_t)(b * NHEAD + h) * S_LEN + sb) * DHEAD;
  f32x4 acc[2][8];
#pragma unroll
  for (int r = 0; r < 2; ++r)
#pragma unroll
    for (int nc = 0; nc < 8; ++nc) acc[r][nc] = zero4();
#pragma unroll
  for (int kc = 0; kc < 4; ++kc)
#pragma unroll
    for (int nc = 0; nc < 8; ++nc) {
      bf16x8 bw = *(const bf16x8*)(Wt + (nc * 16 + row16) * DHEAD + kc * 32 + kgrp * 8);
      acc[0][nc] = mfma16(a[0][kc], bw, acc[0][nc]);
      acc[1][nc] = mfma16(a[1][kc], bw, acc[1][nc]);
    }
#pragma unroll
  for (int r = 0; r < 2; ++r)
#pragma unroll
    for (int nc = 0; nc < 8; ++nc)
#pragma unroll
      for (int i = 0; i < 4; ++i)
        Out[(size_t)(r * 16 + kgrp * 4 + i) * DHEAD + nc * 16 + row16] =
            f2b(acc[r][nc][i]);
}

// ---------------- causal flash attention: 2 blocks/CU, de-locksteped ---------
// QBLK=64, 4 waves = 2q x 2key-halves, LDS 74KB -> 2 independent blocks/CU.
// Same 2 waves/SIMD as r13 but from DIFFERENT blocks (independent barriers):
// phases drift so one block's MFMA/VALU overlaps the other's LDS reads.
// Block = (b,h, qblk-pair {j,63-j}) -> exactly 65 key-tiles each; 512 blocks.
__global__ __launch_bounds__(256) void k_attn(const u16* __restrict__ Qb,
                                              const u16* __restrict__ Kb,
                                              const u16* __restrict__ xT,
                                              u16* __restrict__ Yb) {
  int p = blockIdx.x;                      // 0..511
  int xcd = p & 7;
  int j2 = p >> 3;                         // 0..63
  int bh = xcd + (j2 >= 32 ? 8 : 0);       // 0..15 (same (b,h) per XCD)
  int qpj = j2 & 31;
  int b = bh >> 3, h = bh & 7;

  int tid = threadIdx.x;
  int wid = tid >> 6;                      // 0..3
  int lane = tid & 63;
  int qr = wid >> 1;                       // 0..1 q-subgroup (32 rows)
  int kh = wid & 1;                        // 0..1 key half (32 keys)
  int row16 = lane & 15, kgrp = lane >> 4;

  const u16* Kp = Kb + (size_t)(b * NHEAD + h) * S_LEN * DHEAD;
  const u16* Vt = xT + (size_t)b * DHEAD * S_LEN;

  // fragment-linear: frag f at [f*512 .. f*512+512) u16
  __shared__ __align__(16) u16 Klds[2][8192];       // 32 KB
  __shared__ __align__(16) u16 Vlds[2][8192];       // 32 KB
  __shared__ __align__(16) u16 plds[4][32][40];     // 10 KB (per-wave P)

  // stage one 64-key tile: 16 K-frags + 16 V-frags, 4+4 gll per wave
  auto issue = [&](int k0, int buf) {
#pragma unroll
    for (int fi = 0; fi < 4; ++fi) {
      int f = wid * 4 + fi;
      int kk = (f >> 3) & 1, nk = (f >> 2) & 1, kc = f & 3;
      const u16* src =
          Kp + (size_t)(k0 + kk * 32 + nk * 16 + row16) * DHEAD + kc * 32 + kgrp * 8;
      gll16(src, &Klds[buf][f * 512]);
    }
#pragma unroll
    for (int gi = 0; gi < 4; ++gi) {
      int g = wid * 4 + gi;
      int kk = g >> 3, nc = g & 7;
      const u16* src = Vt + (size_t)(nc * 16 + row16) * S_LEN + k0 + kk * 32 + kgrp * 8;
      gll16(src, &Vlds[buf][g * 512]);
    }
  };

  const float c2 = 0.12754274816295166f;    // (1/sqrt(128)) * log2(e)
  const float clip2 = 14.426950408889634f;  // 10 * log2(e)

  auto runSeg = [&](int qblk) {
    int qb0 = qblk * 64;
    int qw = qb0 + qr * 32;                // this wave's 32 q-rows
    const u16* Qp = Qb + ((size_t)(b * NHEAD + h) * S_LEN + qw) * DHEAD;

    bf16x8 aq[2][4];
#pragma unroll
    for (int r = 0; r < 2; ++r)
#pragma unroll
      for (int kc = 0; kc < 4; ++kc)
        aq[r][kc] = *(const bf16x8*)(Qp + (r * 16 + row16) * DHEAD + kc * 32 + kgrp * 8);

    f32x4 y[2][8];
#pragma unroll
    for (int r = 0; r < 2; ++r)
#pragma unroll
      for (int nc = 0; nc < 8; ++nc) y[r][nc] = zero4();
    f32x4 rs[2];
    rs[0] = zero4();
    rs[1] = zero4();

    // one pass per tile: this wave's 32-key half only
    auto tilecomp = [&](int buf, int k0) {
      bf16x8 kf[8];
#pragma unroll
      for (int nk = 0; nk < 2; ++nk)
#pragma unroll
        for (int kc = 0; kc < 4; ++kc)
          kf[nk * 4 + kc] =
              *(const bf16x8*)&Klds[buf][((kh * 8 + nk * 4 + kc) * 64 + lane) * 8];
      f32x4 sc[2][2];
      sc[0][0] = zero4(); sc[0][1] = zero4(); sc[1][0] = zero4(); sc[1][1] = zero4();
#pragma unroll
      for (int nk = 0; nk < 2; ++nk)
#pragma unroll
        for (int kcc = 0; kcc < 4; ++kcc) {
          sc[0][nk] = mfma16(aq[0][kcc], kf[nk * 4 + kcc], sc[0][nk]);
          sc[1][nk] = mfma16(aq[1][kcc], kf[nk * 4 + kcc], sc[1][nk]);
        }
#pragma unroll
      for (int r = 0; r < 2; ++r)
#pragma unroll
        for (int nk = 0; nk < 2; ++nk) {
          int key = k0 + kh * 32 + nk * 16 + row16;
#pragma unroll
          for (int i = 0; i < 4; ++i) {
            float v = sc[r][nk][i] * c2;
            v = fminf(fmaxf(v, -clip2), clip2);
            float pcur = __builtin_amdgcn_exp2f(v);
            int qrow = qw + r * 16 + kgrp * 4 + i;
            pcur = (key > qrow) ? 0.0f : pcur;   // branchless causal mask
            rs[r][i] += pcur;
            plds[wid][r * 16 + kgrp * 4 + i][nk * 16 + row16] = f2b(pcur);
          }
        }
      bf16x8 ap0 = *(const bf16x8*)&plds[wid][row16][kgrp * 8];
      bf16x8 ap1 = *(const bf16x8*)&plds[wid][16 + row16][kgrp * 8];
#pragma unroll
      for (int nc = 0; nc < 8; ++nc) {
        bf16x8 vf = *(const bf16x8*)&Vlds[buf][((kh * 8 + nc) * 64 + lane) * 8];
        y[0][nc] = mfma16(ap0, vf, y[0][nc]);
        y[1][nc] = mfma16(ap1, vf, y[1][nc]);
      }
    };

    int NT = qblk + 1;   // 64-key tiles covering keys 0..qb0+63
    issue(0, 0);
    __syncthreads();
    for (int t = 0; t < NT; ++t) {
      int k0 = t * 64;
      int cur = t & 1;
      if (t + 1 < NT) issue(k0 + 64, cur ^ 1);  // prefetch under tile compute
      tilecomp(cur, k0);
      __syncthreads();  // drains vmcnt (prefetch landed) + LDS reads done
    }

    // reduce rs over the 16 row16 lanes of each kgrp group
#pragma unroll
    for (int r = 0; r < 2; ++r)
#pragma unroll
      for (int i = 0; i < 4; ++i) {
        float v = rs[r][i];
        v += __shfl_xor(v, 1, 64);
        v += __shfl_xor(v, 2, 64);
        v += __shfl_xor(v, 4, 64);
        v += __shfl_xor(v, 8, 64);
        rs[r][i] = v;
      }

    // combine key halves through the (now dead) K LDS
    float* rscr = (float*)&plds[0][0][0];            // 64 floats used
    float* scr = (float*)&Klds[0][0] + qr * 4096;    // 16KB per q-group
    if (kh == 1) {
#pragma unroll
      for (int r = 0; r < 2; ++r)
#pragma unroll
        for (int nc = 0; nc < 8; ++nc)
          *(f32x4*)&scr[((r * 8 + nc) * 64 + lane) * 4] = y[r][nc];
      if (row16 == 0) {
#pragma unroll
        for (int r = 0; r < 2; ++r)
#pragma unroll
          for (int i = 0; i < 4; ++i)
            rscr[qr * 32 + r * 16 + kgrp * 4 + i] = rs[r][i];
      }
    }
    __syncthreads();
    if (kh == 0) {
#pragma unroll
      for (int r = 0; r < 2; ++r)
#pragma unroll
        for (int nc = 0; nc < 8; ++nc)
          y[r][nc] += *(const f32x4*)&scr[((r * 8 + nc) * 64 + lane) * 4];
#pragma unroll
      for (int r = 0; r < 2; ++r)
#pragma unroll
        for (int i = 0; i < 4; ++i)
          rs[r][i] += rscr[qr * 32 + r * 16 + kgrp * 4 + i];

      u16* Yp = Yb + ((size_t)b * S_LEN + qw) * (NHEAD * DHEAD) + h * DHEAD;
#pragma unroll
      for (int r = 0; r < 2; ++r) {
        float inv[4];
#pragma unroll
        for (int i = 0; i < 4; ++i) inv[i] = 1.0f / rs[r][i];
#pragma unroll
        for (int nc = 0; nc < 8; ++nc)
#pragma unroll
          for (int i = 0; i < 4; ++i)
            Yp[(size_t)(r * 16 + kgrp * 4 + i) * (NHEAD * DHEAD) + nc * 16 + row16] =
                f2b(y[r][nc][i] * inv[i]);
      }
    }
    __syncthreads();  // scratch reads done before next segment stages over it
  };

  runSeg(63 - qpj);   // long segment first
  runSeg(qpj);        // complementary short: 65 tiles for every block, flat
}

// ---------------- output projection: 4 waves/block ----------------
__global__ __launch_bounds__(256) void k_oproj(const u16* __restrict__ Yb,
                                               const u16* __restrict__ WoB,
                                               float* __restrict__ out) {
  int wid = threadIdx.x >> 6;
  int lane = threadIdx.x & 63;
  int mb = (blockIdx.x * 4 + wid) * 32 + blockIdx.y * 16;
  int nb = blockIdx.z * 64;
  int row16 = lane & 15, kgrp = lane >> 4;
  f32x4 acc[4];
#pragma unroll
  for (int nc = 0; nc < 4; ++nc) acc[nc] = zero4();
#pragma unroll 4
  for (int kc = 0; kc < 32; ++kc) {
    bf16x8 a0 = *(const bf16x8*)(Yb + (size_t)(mb + row16) * 1024 + kc * 32 + kgrp * 8);
#pragma unroll
    for (int nc = 0; nc < 4; ++nc) {
      bf16x8 bw =
          *(const bf16x8*)(WoB + (size_t)(nb + nc * 16 + row16) * 1024 + kc * 32 + kgrp * 8);
      acc[nc] = mfma16(a0, bw, acc[nc]);
    }
  }
#pragma unroll
  for (int nc = 0; nc < 4; ++nc)
#pragma unroll
    for (int i = 0; i < 4; ++i)
      out[(size_t)(mb + kgrp * 4 + i) * DHEAD + nb + nc * 16 + row16] = acc[nc][i];
}

extern "C" void kernel_launch(void* const* d_in, const int* in_sizes, int n_in,
                              void* d_out, int out_size, void* d_ws, size_t ws_size,
                              hipStream_t stream) {
  const float* x = (const float*)d_in[0];
  const float* Wq = (const float*)d_in[1];
  const float* Wk = (const float*)d_in[2];
  const float* Wo = (const float*)d_in[3];
  float* out = (float*)d_out;

  char* ws = (char*)d_ws;
  size_t off = 0;
  auto alloc = [&](size_t bytes) -> void* {
    void* p = ws + off;
    off += (bytes + 255) & ~(size_t)255;
    return p;
  };
  const size_t nx = (size_t)NBATCH * S_LEN * DHEAD;
  const size_t nqk = (size_t)NBATCH * NHEAD * S_LEN * DHEAD;
  u16* xb = (u16*)alloc(nx * 2);
  u16* xT = (u16*)alloc(nx * 2);
  u16* Wqt = (u16*)alloc((size_t)NHEAD * DHEAD * DHEAD * 2);
  u16* Wkt = (u16*)alloc((size_t)NHEAD * DHEAD * DHEAD * 2);
  u16* WoB = (u16*)alloc((size_t)DHEAD * NHEAD * DHEAD * 2);
  u16* Qb = (u16*)alloc(nqk * 2);
  u16* Kb = (u16*)alloc(nqk * 2);
  u16* Yb = (u16*)alloc(nqk * 2);
  (void)ws_size;

  k_conv_x<<<dim3(nx / 256), dim3(256), 0, stream>>>(x, xb, xT);
  k_conv_w<<<dim3(131072 / 256), dim3(256), 0, stream>>>(Wq, Wk, Wo, Wqt, Wkt, WoB);
  k_proj<<<dim3(S_LEN / 32 / 4, NHEAD, 2 * NBATCH), dim3(256), 0, stream>>>(xb, Wqt, Wkt, Qb, Kb);
  k_attn<<<dim3(512), dim3(256), 0, stream>>>(Qb, Kb, xT, Yb);
  k_oproj<<<dim3((NBATCH * S_LEN) / 32 / 4, 2, 2), dim3(256), 0, stream>>>(Yb, WoB, out);
}

// Round 15
// 164.931 us; speedup vs baseline: 1.1904x; 1.1904x over previous
//
#include <hip/hip_runtime.h>
#include <hip/hip_bf16.h>

typedef unsigned short u16;
typedef unsigned int u32;
typedef __attribute__((ext_vector_type(8))) short bf16x8;
typedef __attribute__((ext_vector_type(4))) float f32x4;
typedef __attribute__((ext_vector_type(16))) float f32x16;
typedef __attribute__((ext_vector_type(2))) unsigned int u32x2;
typedef __attribute__((ext_vector_type(4))) unsigned int u32x4;

#define S_LEN 4096
#define DHEAD 128
#define NHEAD 8
#define NBATCH 2

__device__ __forceinline__ u16 f2b(float f) {
  __hip_bfloat16 h = __float2bfloat16(f);
  return *(u16*)&h;
}

__device__ __forceinline__ f32x4 mfma16(bf16x8 a, bf16x8 b, f32x4 c) {
  return __builtin_amdgcn_mfma_f32_16x16x32_bf16(a, b, c, 0, 0, 0);
}
__device__ __forceinline__ f32x16 mfma32(bf16x8 a, bf16x8 b, f32x16 c) {
  return __builtin_amdgcn_mfma_f32_32x32x16_bf16(a, b, c, 0, 0, 0);
}

__device__ __forceinline__ f32x4 zero4() { f32x4 z = {0.f, 0.f, 0.f, 0.f}; return z; }

__device__ __forceinline__ u32 cvtpk(float lo, float hi) {
  u32 r;
  asm("v_cvt_pk_bf16_f32 %0, %1, %2" : "=v"(r) : "v"(lo), "v"(hi));
  return r;
}
__device__ __forceinline__ u32x2 pswap(u32 a, u32 b) {
  // v_permlane32_swap: x = {a.lo32lanes, b.lo32lanes}, y = {a.hi32, b.hi32}
  return __builtin_amdgcn_permlane32_swap(a, b, false, false);
}

// async global->LDS, 16B/lane; LDS dest = wave-uniform base + lane*16
__device__ __forceinline__ void gll16(const u16* g, u16* l) {
  __builtin_amdgcn_global_load_lds(
      (const __attribute__((address_space(1))) u32*)g,
      (__attribute__((address_space(3))) u32*)l, 16, 0, 0);
}

// ---------------- converts ----------------
// xb row-major bf16 (k_proj input); VbF: V in 32x32-MFMA B-fragment order.
// VbF frag g = kh*8 + m2*4 + db at [((b*64+t64)*16+g)*512 + l*8 + j]:
//   key = t64*64+kh*32+m2*16+(l>>5)*8+j, dout = db*32+(l&31)
__global__ void k_conv_x(const float* __restrict__ x, u16* __restrict__ xb,
                         u16* __restrict__ VbF) {
  int idx = blockIdx.x * blockDim.x + threadIdx.x;
  float v = x[idx];
  u16 bv = f2b(v);
  xb[idx] = bv;
  int d = idx & 127;
  int bs = idx >> 7;
  int b = bs >> 12;
  int s = bs & 4095;  // key
  int t64 = s >> 6, kh = (s >> 5) & 1, m2 = (s >> 4) & 1;
  int h5v = (s >> 3) & 1, j = s & 7;
  int db = d >> 5;
  int l = (d & 31) + 32 * h5v;
  int g = kh * 8 + m2 * 4 + db;
  VbF[(((size_t)b * 64 + t64) * 16 + g) * 512 + l * 8 + j] = bv;
}

__global__ void k_conv_w(const float* __restrict__ Wq, const float* __restrict__ Wk,
                         const float* __restrict__ Wo, u16* __restrict__ Wqt,
                         u16* __restrict__ Wkt, u16* __restrict__ WoB) {
  int idx = blockIdx.x * blockDim.x + threadIdx.x;
  int h = idx >> 14;
  int d = (idx >> 7) & 127;
  int e = idx & 127;
  int t = (h << 14) + (e << 7) + d;
  Wqt[t] = f2b(Wq[idx]);
  Wkt[t] = f2b(Wk[idx]);
  WoB[idx] = f2b(Wo[idx]);
}

// ---------------- Q/K projection: 4 waves/block ----------------
// Q -> row-major Qb; K -> KbF fragment order: frag f = kh*8+m at
// [((bh*64+t64)*16+f)*512 + l*8 + j]: key=t64*64+kh*32+(l&31), d=m*16+(l>>5)*8+j
__global__ __launch_bounds__(256) void k_proj(const u16* __restrict__ xb,
                                              const u16* __restrict__ Wqt,
                                              const u16* __restrict__ Wkt,
                                              u16* __restrict__ Qb, u16* __restrict__ KbF) {
  int wid = threadIdx.x >> 6;
  int lane = threadIdx.x & 63;
  int qt = blockIdx.x * 4 + wid;
  int h = blockIdx.y, z = blockIdx.z;
  int b = z >> 1, w = z & 1;
  int bh = b * NHEAD + h;
  int row16 = lane & 15, kgrp = lane >> 4;
  int sb = qt * 32;
  const u16* xp = xb + ((size_t)b * S_LEN + sb) * DHEAD;
  bf16x8 a[2][4];
#pragma unroll
  for (int r = 0; r < 2; ++r)
#pragma unroll
    for (int kc = 0; kc < 4; ++kc)
      a[r][kc] = *(const bf16x8*)(xp + (r * 16 + row16) * DHEAD + kc * 32 + kgrp * 8);

  const u16* Wt = (w == 0 ? Wqt : Wkt) + (size_t)h * DHEAD * DHEAD;
  f32x4 acc[2][8];
#pragma unroll
  for (int r = 0; r < 2; ++r)
#pragma unroll
    for (int nc = 0; nc < 8; ++nc) acc[r][nc] = zero4();
#pragma unroll
  for (int kc = 0; kc < 4; ++kc)
#pragma unroll
    for (int nc = 0; nc < 8; ++nc) {
      bf16x8 bw = *(const bf16x8*)(Wt + (nc * 16 + row16) * DHEAD + kc * 32 + kgrp * 8);
      acc[0][nc] = mfma16(a[0][kc], bw, acc[0][nc]);
      acc[1][nc] = mfma16(a[1][kc], bw, acc[1][nc]);
    }
  if (w == 0) {
    u16* Out = Qb + ((size_t)bh * S_LEN + sb) * DHEAD;
#pragma unroll
    for (int r = 0; r < 2; ++r)
#pragma unroll
      for (int nc = 0; nc < 8; ++nc)
#pragma unroll
        for (int i = 0; i < 4; ++i)
          Out[(size_t)(r * 16 + kgrp * 4 + i) * DHEAD + nc * 16 + row16] =
              f2b(acc[r][nc][i]);
  } else {
#pragma unroll
    for (int r = 0; r < 2; ++r)
#pragma unroll
      for (int nc = 0; nc < 8; ++nc)
#pragma unroll
        for (int i = 0; i < 4; ++i) {
          int key = sb + r * 16 + kgrp * 4 + i;
          int e = nc * 16 + row16;
          int t64 = key >> 6, kh = (key >> 5) & 1;
          int m = e >> 4;
          int l = (key & 31) + 32 * ((e >> 3) & 1);
          int j = e & 7;
          int f = kh * 8 + m;
          KbF[(((size_t)bh * 64 + t64) * 16 + f) * 512 + l * 8 + j] = f2b(acc[r][nc][i]);
        }
  }
}

// ---------------- causal flash attention: swapped-QK in-register softmax -----
// r13 frame: QBLK=128, 8 waves = 4 qr x 2 kh, balanced pairs {j,31-j}, 68 tiles.
// 32x32 MFMA, S = mfma(K,Q): lane holds 16 scores of ONE q (q=lane&31).
// Softmax fully in registers; P->PV A-operand via cvt_pk + permlane32_swap.
// NO P LDS buffer. K/V staged via gll from fragment-ordered KbF/VbF.
__global__ __launch_bounds__(512) void k_attn(const u16* __restrict__ Qb,
                                              const u16* __restrict__ KbF,
                                              const u16* __restrict__ VbF,
                                              u16* __restrict__ Yb) {
  int p = blockIdx.x;                      // 0..255
  int xcd = p & 7;
  int j2 = p >> 3;                         // 0..31
  int bh = xcd + (j2 >= 16 ? 8 : 0);       // 0..15 (same (b,h) per XCD)
  int qpj = j2 & 15;
  int b = bh >> 3, h = bh & 7;

  int tid = threadIdx.x;
  int wid = tid >> 6;                      // 0..7
  int lane = tid & 63;
  int qr = wid >> 1;                       // 0..3 (32 q-rows each)
  int kh = wid & 1;                        // key half of 64-key tile
  int l31 = lane & 31, h5 = lane >> 5;

  __shared__ __align__(16) u16 Klds[2][8192];   // 32 KB
  __shared__ __align__(16) u16 Vlds[2][8192];   // 32 KB
  __shared__ float rsbuf[2][4][32];             // 1 KB

  const u16* Kbase = KbF + (size_t)bh * 64 * 16 * 512;
  const u16* Vbase = VbF + (size_t)b * 64 * 16 * 512;

  // stage one 64-key tile: 16 K-frags + 16 V-frags (1KB contiguous each)
  auto issue = [&](int k0, int buf) {
    int t64 = k0 >> 6;
    const u16* Ks = Kbase + (size_t)t64 * 16 * 512;
    const u16* Vs = Vbase + (size_t)t64 * 16 * 512;
#pragma unroll
    for (int fi = 0; fi < 2; ++fi) {
      int f = wid * 2 + fi;
      gll16(Ks + f * 512 + lane * 8, &Klds[buf][f * 512]);
    }
#pragma unroll
    for (int gi = 0; gi < 2; ++gi) {
      int g = wid * 2 + gi;
      gll16(Vs + g * 512 + lane * 8, &Vlds[buf][g * 512]);
    }
  };

  const float c2 = 0.12754274816295166f;    // (1/sqrt(128)) * log2(e)
  const float clip2 = 14.426950408889634f;  // 10 * log2(e)

  auto runSeg = [&](int qblk) {
    int qb0 = qblk * 128;
    int qw = qb0 + qr * 32;
    int qrow = qw + l31;                   // this lane's q-row
    const u16* Qp = Qb + ((size_t)bh * S_LEN + qw) * DHEAD;

    // Q as B-operand: bq[m]: lane l holds Q[q=l31][d=m*16+h5*8+j]
    bf16x8 bq[8];
#pragma unroll
    for (int m = 0; m < 8; ++m)
      bq[m] = *(const bf16x8*)(Qp + (size_t)l31 * DHEAD + m * 16 + h5 * 8);

    f32x16 y0 = {0.f}, y1 = {0.f}, y2 = {0.f}, y3 = {0.f};
#pragma unroll
    for (int i = 0; i < 16; ++i) { y0[i] = 0.f; y1[i] = 0.f; y2[i] = 0.f; y3[i] = 0.f; }
    float rs = 0.f;

    auto tilecomp = [&](int buf, int k0) {
      // QK^T swapped: S[key][q], A=K frag (key rows), B=Q (q cols)
      f32x16 sc;
#pragma unroll
      for (int i = 0; i < 16; ++i) sc[i] = 0.f;
#pragma unroll
      for (int m = 0; m < 8; ++m) {
        bf16x8 kf = *(const bf16x8*)&Klds[buf][((kh * 8 + m) * 512) + lane * 8];
        sc = mfma32(kf, bq[m], sc);
      }
      // softmax per-lane: all 16 scores belong to q=l31
      float pf[16];
      int kb = k0 + kh * 32 + h5 * 4;
#pragma unroll
      for (int reg = 0; reg < 16; ++reg) {
        int key = kb + (reg & 3) + 8 * (reg >> 2);
        float v = sc[reg] * c2;
        v = fminf(fmaxf(v, -clip2), clip2);
        float pc = __builtin_amdgcn_exp2f(v);
        pc = (key > qrow) ? 0.0f : pc;
        rs += pc;
        pf[reg] = pc;
      }
      // pack P -> PV A-fragments (keys m2*16 + h5*8 + j per frag)
      u32 cv0 = cvtpk(pf[0], pf[1]), cv1 = cvtpk(pf[2], pf[3]);
      u32 cv2 = cvtpk(pf[4], pf[5]), cv3 = cvtpk(pf[6], pf[7]);
      u32 cv4 = cvtpk(pf[8], pf[9]), cv5 = cvtpk(pf[10], pf[11]);
      u32 cv6 = cvtpk(pf[12], pf[13]), cv7 = cvtpk(pf[14], pf[15]);
      u32x2 s0 = pswap(cv0, cv2);  // x: w0 both halves; y: w2
      u32x2 s1 = pswap(cv1, cv3);
      u32x2 s2 = pswap(cv4, cv6);
      u32x2 s3 = pswap(cv5, cv7);
      u32x4 pa0u = {s0.x, s1.x, s0.y, s1.y};
      u32x4 pa1u = {s2.x, s3.x, s2.y, s3.y};
      bf16x8 pa0 = __builtin_bit_cast(bf16x8, pa0u);
      bf16x8 pa1 = __builtin_bit_cast(bf16x8, pa1u);
      // PV: y[db] += P(16 keys m2=0) * V + P(m2=1) * V
      {
        bf16x8 vf = *(const bf16x8*)&Vlds[buf][((kh * 8 + 0) * 512) + lane * 8];
        y0 = mfma32(pa0, vf, y0);
        vf = *(const bf16x8*)&Vlds[buf][((kh * 8 + 4) * 512) + lane * 8];
        y0 = mfma32(pa1, vf, y0);
        vf = *(const bf16x8*)&Vlds[buf][((kh * 8 + 1) * 512) + lane * 8];
        y1 = mfma32(pa0, vf, y1);
        vf = *(const bf16x8*)&Vlds[buf][((kh * 8 + 5) * 512) + lane * 8];
        y1 = mfma32(pa1, vf, y1);
        vf = *(const bf16x8*)&Vlds[buf][((kh * 8 + 2) * 512) + lane * 8];
        y2 = mfma32(pa0, vf, y2);
        vf = *(const bf16x8*)&Vlds[buf][((kh * 8 + 6) * 512) + lane * 8];
        y2 = mfma32(pa1, vf, y2);
        vf = *(const bf16x8*)&Vlds[buf][((kh * 8 + 3) * 512) + lane * 8];
        y3 = mfma32(pa0, vf, y3);
        vf = *(const bf16x8*)&Vlds[buf][((kh * 8 + 7) * 512) + lane * 8];
        y3 = mfma32(pa1, vf, y3);
      }
    };

    int NT = 2 * qblk + 2;
    issue(0, 0);
    __syncthreads();
    for (int t = 0; t < NT; ++t) {
      int k0 = t * 64;
      int cur = t & 1;
      if (t + 1 < NT) issue(k0 + 64, cur ^ 1);
      tilecomp(cur, k0);
      __syncthreads();
    }

    // rs: combine the two h5 key-subsets (same q)
    rs += __shfl_xor(rs, 32, 64);

    // key-half (kh) combine through dead K/V LDS (f32 scratch, lane-linear)
    float* scr = (qr < 2) ? ((float*)&Klds[0][0] + qr * 4096)
                          : ((float*)&Vlds[0][0] + (qr - 2) * 4096);
    if (kh == 1) {
#pragma unroll
      for (int db = 0; db < 4; ++db) {
        const f32x16& yv = (db == 0) ? y0 : (db == 1) ? y1 : (db == 2) ? y2 : y3;
#pragma unroll
        for (int r4 = 0; r4 < 4; ++r4) {
          f32x4 ch = {yv[r4 * 4 + 0], yv[r4 * 4 + 1], yv[r4 * 4 + 2], yv[r4 * 4 + 3]};
          *(f32x4*)&scr[((db * 4 + r4) * 64 + lane) * 4] = ch;
        }
      }
      if (lane < 32) rsbuf[1][qr][lane] = rs;
    }
    __syncthreads();
    if (kh == 0) {
      rs += rsbuf[1][qr][l31];
      float inv = 1.0f / rs;
      if (lane < 32) rsbuf[0][qr][lane] = inv;
#pragma unroll
      for (int db = 0; db < 4; ++db) {
        f32x16& yv = (db == 0) ? y0 : (db == 1) ? y1 : (db == 2) ? y2 : y3;
#pragma unroll
        for (int r4 = 0; r4 < 4; ++r4) {
          f32x4 ch = *(const f32x4*)&scr[((db * 4 + r4) * 64 + lane) * 4];
#pragma unroll
          for (int k = 0; k < 4; ++k) yv[r4 * 4 + k] += ch[k];
        }
      }
      // write Y: element (q' = (reg&3)+8*(reg>>2)+4*h5, dout = db*32+l31)
      u16* Yp = Yb + ((size_t)b * S_LEN + qw) * (NHEAD * DHEAD) + h * DHEAD;
#pragma unroll
      for (int db = 0; db < 4; ++db) {
        const f32x16& yv = (db == 0) ? y0 : (db == 1) ? y1 : (db == 2) ? y2 : y3;
#pragma unroll
        for (int reg = 0; reg < 16; ++reg) {
          int qp2 = (reg & 3) + 8 * (reg >> 2) + 4 * h5;
          float rv = rsbuf[0][qr][qp2];   // broadcast read (uniform per 32-half)
          Yp[(size_t)qp2 * (NHEAD * DHEAD) + db * 32 + l31] = f2b(yv[reg] * rv);
        }
      }
    }
    __syncthreads();  // scratch + rsbuf reads done before next segment stages
  };

  runSeg(31 - qpj);   // long segment first
  runSeg(qpj);        // complementary short: 68 tiles for every block, flat
}

// ---------------- output projection: 4 waves/block ----------------
__global__ __launch_bounds__(256) void k_oproj(const u16* __restrict__ Yb,
                                               const u16* __restrict__ WoB,
                                               float* __restrict__ out) {
  int wid = threadIdx.x >> 6;
  int lane = threadIdx.x & 63;
  int mb = (blockIdx.x * 4 + wid) * 32 + blockIdx.y * 16;
  int nb = blockIdx.z * 64;
  int row16 = lane & 15, kgrp = lane >> 4;
  f32x4 acc[4];
#pragma unroll
  for (int nc = 0; nc < 4; ++nc) acc[nc] = zero4();
#pragma unroll 4
  for (int kc = 0; kc < 32; ++kc) {
    bf16x8 a0 = *(const bf16x8*)(Yb + (size_t)(mb + row16) * 1024 + kc * 32 + kgrp * 8);
#pragma unroll
    for (int nc = 0; nc < 4; ++nc) {
      bf16x8 bw =
          *(const bf16x8*)(WoB + (size_t)(nb + nc * 16 + row16) * 1024 + kc * 32 + kgrp * 8);
      acc[nc] = mfma16(a0, bw, acc[nc]);
    }
  }
#pragma unroll
  for (int nc = 0; nc < 4; ++nc)
#pragma unroll
    for (int i = 0; i < 4; ++i)
      out[(size_t)(mb + kgrp * 4 + i) * DHEAD + nb + nc * 16 + row16] = acc[nc][i];
}

extern "C" void kernel_launch(void* const* d_in, const int* in_sizes, int n_in,
                              void* d_out, int out_size, void* d_ws, size_t ws_size,
                              hipStream_t stream) {
  const float* x = (const float*)d_in[0];
  const float* Wq = (const float*)d_in[1];
  const float* Wk = (const float*)d_in[2];
  const float* Wo = (const float*)d_in[3];
  float* out = (float*)d_out;

  char* ws = (char*)d_ws;
  size_t off = 0;
  auto alloc = [&](size_t bytes) -> void* {
    void* p = ws + off;
    off += (bytes + 255) & ~(size_t)255;
    return p;
  };
  const size_t nx = (size_t)NBATCH * S_LEN * DHEAD;
  const size_t nqk = (size_t)NBATCH * NHEAD * S_LEN * DHEAD;
  u16* xb = (u16*)alloc(nx * 2);
  u16* VbF = (u16*)alloc(nx * 2);
  u16* Wqt = (u16*)alloc((size_t)NHEAD * DHEAD * DHEAD * 2);
  u16* Wkt = (u16*)alloc((size_t)NHEAD * DHEAD * DHEAD * 2);
  u16* WoB = (u16*)alloc((size_t)DHEAD * NHEAD * DHEAD * 2);
  u16* Qb = (u16*)alloc(nqk * 2);
  u16* KbF = (u16*)alloc(nqk * 2);
  u16* Yb = (u16*)alloc(nqk * 2);
  (void)ws_size;

  k_conv_x<<<dim3(nx / 256), dim3(256), 0, stream>>>(x, xb, VbF);
  k_conv_w<<<dim3(131072 / 256), dim3(256), 0, stream>>>(Wq, Wk, Wo, Wqt, Wkt, WoB);
  k_proj<<<dim3(S_LEN / 32 / 4, NHEAD, 2 * NBATCH), dim3(256), 0, stream>>>(xb, Wqt, Wkt, Qb, KbF);
  k_attn<<<dim3(256), dim3(512), 0, stream>>>(Qb, KbF, VbF, Yb);
  k_oproj<<<dim3((NBATCH * S_LEN) / 32 / 4, 2, 2), dim3(256), 0, stream>>>(Yb, WoB, out);
}

// Round 16
// 158.395 us; speedup vs baseline: 1.2396x; 1.0413x over previous
//
#include <hip/hip_runtime.h>
#include <hip/hip_bf16.h>

typedef unsigned short u16;
typedef unsigned int u32;
typedef __attribute__((ext_vector_type(8))) short bf16x8;
typedef __attribute__((ext_vector_type(4))) float f32x4;
typedef __attribute__((ext_vector_type(16))) float f32x16;
typedef __attribute__((ext_vector_type(2))) unsigned int u32x2;
typedef __attribute__((ext_vector_type(4))) unsigned int u32x4;

#define S_LEN 4096
#define DHEAD 128
#define NHEAD 8
#define NBATCH 2

__device__ __forceinline__ u16 f2b(float f) {
  __hip_bfloat16 h = __float2bfloat16(f);
  return *(u16*)&h;
}

__device__ __forceinline__ f32x4 mfma16(bf16x8 a, bf16x8 b, f32x4 c) {
  return __builtin_amdgcn_mfma_f32_16x16x32_bf16(a, b, c, 0, 0, 0);
}
__device__ __forceinline__ f32x16 mfma32(bf16x8 a, bf16x8 b, f32x16 c) {
  return __builtin_amdgcn_mfma_f32_32x32x16_bf16(a, b, c, 0, 0, 0);
}

__device__ __forceinline__ f32x4 zero4() { f32x4 z = {0.f, 0.f, 0.f, 0.f}; return z; }

__device__ __forceinline__ u32 cvtpk(float lo, float hi) {
  u32 r;
  asm("v_cvt_pk_bf16_f32 %0, %1, %2" : "=v"(r) : "v"(lo), "v"(hi));
  return r;
}
__device__ __forceinline__ u32x2 pswap(u32 a, u32 b) {
  return __builtin_amdgcn_permlane32_swap(a, b, false, false);
}

// async global->LDS, 16B/lane; LDS dest = wave-uniform base + lane*16
__device__ __forceinline__ void gll16(const u16* g, u16* l) {
  __builtin_amdgcn_global_load_lds(
      (const __attribute__((address_space(1))) u32*)g,
      (__attribute__((address_space(3))) u32*)l, 16, 0, 0);
}

// ---------------- converts ----------------
// xb row-major bf16; VbF: V in 32x32-MFMA B-fragment order.
// VbF frag g = kh*8 + m2*4 + db at [((b*64+t64)*16+g)*512 + l*8 + j]:
//   key = t64*64+kh*32+m2*16+(l>>5)*8+j, dout = db*32+(l&31)
__global__ void k_conv_x(const float* __restrict__ x, u16* __restrict__ xb,
                         u16* __restrict__ VbF) {
  int idx = blockIdx.x * blockDim.x + threadIdx.x;
  float v = x[idx];
  u16 bv = f2b(v);
  xb[idx] = bv;
  int d = idx & 127;
  int bs = idx >> 7;
  int b = bs >> 12;
  int s = bs & 4095;  // key
  int t64 = s >> 6, kh = (s >> 5) & 1, m2 = (s >> 4) & 1;
  int h5v = (s >> 3) & 1, j = s & 7;
  int db = d >> 5;
  int l = (d & 31) + 32 * h5v;
  int g = kh * 8 + m2 * 4 + db;
  VbF[(((size_t)b * 64 + t64) * 16 + g) * 512 + l * 8 + j] = bv;
}

__global__ void k_conv_w(const float* __restrict__ Wq, const float* __restrict__ Wk,
                         const float* __restrict__ Wo, u16* __restrict__ Wqt,
                         u16* __restrict__ Wkt, u16* __restrict__ WoB) {
  int idx = blockIdx.x * blockDim.x + threadIdx.x;
  int h = idx >> 14;
  int d = (idx >> 7) & 127;
  int e = idx & 127;
  int t = (h << 14) + (e << 7) + d;
  Wqt[t] = f2b(Wq[idx]);
  Wkt[t] = f2b(Wk[idx]);
  WoB[idx] = f2b(Wo[idx]);
}

// ---------------- Q/K projection: 4 waves/block ----------------
// Q -> row-major Qb; K -> KbF fragment order: frag f = kh*8+m at
// [((bh*64+t64)*16+f)*512 + l*8 + j]: key=t64*64+kh*32+(l&31), d=m*16+(l>>5)*8+j
__global__ __launch_bounds__(256) void k_proj(const u16* __restrict__ xb,
                                              const u16* __restrict__ Wqt,
                                              const u16* __restrict__ Wkt,
                                              u16* __restrict__ Qb, u16* __restrict__ KbF) {
  int wid = threadIdx.x >> 6;
  int lane = threadIdx.x & 63;
  int qt = blockIdx.x * 4 + wid;
  int h = blockIdx.y, z = blockIdx.z;
  int b = z >> 1, w = z & 1;
  int bh = b * NHEAD + h;
  int row16 = lane & 15, kgrp = lane >> 4;
  int sb = qt * 32;
  const u16* xp = xb + ((size_t)b * S_LEN + sb) * DHEAD;
  bf16x8 a[2][4];
#pragma unroll
  for (int r = 0; r < 2; ++r)
#pragma unroll
    for (int kc = 0; kc < 4; ++kc)
      a[r][kc] = *(const bf16x8*)(xp + (r * 16 + row16) * DHEAD + kc * 32 + kgrp * 8);

  const u16* Wt = (w == 0 ? Wqt : Wkt) + (size_t)h * DHEAD * DHEAD;
  f32x4 acc[2][8];
#pragma unroll
  for (int r = 0; r < 2; ++r)
#pragma unroll
    for (int nc = 0; nc < 8; ++nc) acc[r][nc] = zero4();
#pragma unroll
  for (int kc = 0; kc < 4; ++kc)
#pragma unroll
    for (int nc = 0; nc < 8; ++nc) {
      bf16x8 bw = *(const bf16x8*)(Wt + (nc * 16 + row16) * DHEAD + kc * 32 + kgrp * 8);
      acc[0][nc] = mfma16(a[0][kc], bw, acc[0][nc]);
      acc[1][nc] = mfma16(a[1][kc], bw, acc[1][nc]);
    }
  if (w == 0) {
    u16* Out = Qb + ((size_t)bh * S_LEN + sb) * DHEAD;
#pragma unroll
    for (int r = 0; r < 2; ++r)
#pragma unroll
      for (int nc = 0; nc < 8; ++nc)
#pragma unroll
        for (int i = 0; i < 4; ++i)
          Out[(size_t)(r * 16 + kgrp * 4 + i) * DHEAD + nc * 16 + row16] =
              f2b(acc[r][nc][i]);
  } else {
#pragma unroll
    for (int r = 0; r < 2; ++r)
#pragma unroll
      for (int nc = 0; nc < 8; ++nc)
#pragma unroll
        for (int i = 0; i < 4; ++i) {
          int key = sb + r * 16 + kgrp * 4 + i;
          int e = nc * 16 + row16;
          int t64 = key >> 6, kh = (key >> 5) & 1;
          int m = e >> 4;
          int l = (key & 31) + 32 * ((e >> 3) & 1);
          int j = e & 7;
          int f = kh * 8 + m;
          KbF[(((size_t)bh * 64 + t64) * 16 + f) * 512 + l * 8 + j] = f2b(acc[r][nc][i]);
        }
  }
}

// ---------------- causal flash attention: in-reg softmax + V-in-reg ----------
// QBLK=128, 8 waves = 4 qr x 2 kh, balanced pairs {j,31-j}, 68 tiles, flat.
// K staged to LDS (16 frags, gll). V loaded straight to REGISTERS from
// fragment-ordered VbF (L2-resident) -> LDS reads/tile/CU halved (128->64).
// Softmax in registers (swapped QK, cvt_pk+permlane pack). Masked tiles take
// a separate wave-uniform branch. setprio(1) wraps the MFMA clusters.
__global__ __launch_bounds__(512) void k_attn(const u16* __restrict__ Qb,
                                              const u16* __restrict__ KbF,
                                              const u16* __restrict__ VbF,
                                              u16* __restrict__ Yb) {
  int p = blockIdx.x;                      // 0..255
  int xcd = p & 7;
  int j2 = p >> 3;                         // 0..31
  int bh = xcd + (j2 >= 16 ? 8 : 0);       // 0..15 (same (b,h) per XCD)
  int qpj = j2 & 15;
  int b = bh >> 3, h = bh & 7;

  int tid = threadIdx.x;
  int wid = tid >> 6;                      // 0..7
  int lane = tid & 63;
  int qr = wid >> 1;                       // 0..3 (32 q-rows each)
  int kh = wid & 1;                        // key half of 64-key tile
  int l31 = lane & 31, h5 = lane >> 5;

  __shared__ __align__(16) u16 Klds[2][8192];   // 32 KB (K frags only)
  __shared__ __align__(16) float Scr[8192];     // 32 KB combine scratch
  __shared__ float rsbuf[2][4][32];             // 1 KB

  const u16* Kbase = KbF + (size_t)bh * 64 * 16 * 512;
  const u16* Vbase = VbF + (size_t)b * 64 * 16 * 512;

  // stage one 64-key K tile: 16 frags (1KB contiguous each), 2 gll per wave
  auto issue = [&](int k0, int buf) {
    const u16* Ks = Kbase + (size_t)(k0 >> 6) * 16 * 512;
#pragma unroll
    for (int fi = 0; fi < 2; ++fi) {
      int f = wid * 2 + fi;
      gll16(Ks + f * 512 + lane * 8, &Klds[buf][f * 512]);
    }
  };
  // V frags straight to registers (this wave's kh half: 8 frags = 1KB/instr)
  auto vload = [&](bf16x8 (&dst)[8], int k0) {
    const u16* Vs = Vbase + ((size_t)(k0 >> 6) * 16 + kh * 8) * 512 + lane * 8;
#pragma unroll
    for (int g = 0; g < 8; ++g) dst[g] = *(const bf16x8*)(Vs + g * 512);
  };

  const float c2 = 0.12754274816295166f;    // (1/sqrt(128)) * log2(e)
  const float clip2 = 14.426950408889634f;  // 10 * log2(e)

  auto runSeg = [&](int qblk) {
    int qb0 = qblk * 128;
    int qw = qb0 + qr * 32;
    int qrow = qw + l31;                   // this lane's q-row
    const u16* Qp = Qb + ((size_t)bh * S_LEN + qw) * DHEAD;

    bf16x8 bq[8];
#pragma unroll
    for (int m = 0; m < 8; ++m)
      bq[m] = *(const bf16x8*)(Qp + (size_t)l31 * DHEAD + m * 16 + h5 * 8);

    f32x16 y0, y1, y2, y3;
#pragma unroll
    for (int i = 0; i < 16; ++i) { y0[i] = 0.f; y1[i] = 0.f; y2[i] = 0.f; y3[i] = 0.f; }
    float rs = 0.f;

    bf16x8 vA[8], vB[8];

    auto tilecomp = [&](int buf, int k0, bf16x8 (&vc)[8], bf16x8 (&vn)[8], int kn0) {
      // QK^T swapped: S[key][q]
      f32x16 sc;
#pragma unroll
      for (int i = 0; i < 16; ++i) sc[i] = 0.f;
      __builtin_amdgcn_s_setprio(1);
#pragma unroll
      for (int m = 0; m < 8; ++m) {
        bf16x8 kf = *(const bf16x8*)&Klds[buf][((kh * 8 + m) * 512) + lane * 8];
        sc = mfma32(kf, bq[m], sc);
      }
      __builtin_amdgcn_s_setprio(0);
      vload(vn, kn0);   // next tile's V: in flight under softmax+PV+QK(next)

      // per-lane softmax: all 16 scores belong to q = l31
      float pf[16];
      int kb = k0 + kh * 32 + h5 * 4;
      bool nomask = (k0 + kh * 32 + 31) <= qw;   // wave-uniform
      if (nomask) {
#pragma unroll
        for (int reg = 0; reg < 16; ++reg) {
          float v = __builtin_amdgcn_fmed3f(sc[reg] * c2, -clip2, clip2);
          float pc = __builtin_amdgcn_exp2f(v);
          rs += pc;
          pf[reg] = pc;
        }
      } else {
#pragma unroll
        for (int reg = 0; reg < 16; ++reg) {
          int key = kb + (reg & 3) + 8 * (reg >> 2);
          float v = __builtin_amdgcn_fmed3f(sc[reg] * c2, -clip2, clip2);
          float pc = __builtin_amdgcn_exp2f(v);
          pc = (key > qrow) ? 0.0f : pc;
          rs += pc;
          pf[reg] = pc;
        }
      }
      // pack P -> PV A-fragments
      u32 cv0 = cvtpk(pf[0], pf[1]), cv1 = cvtpk(pf[2], pf[3]);
      u32 cv2 = cvtpk(pf[4], pf[5]), cv3 = cvtpk(pf[6], pf[7]);
      u32 cv4 = cvtpk(pf[8], pf[9]), cv5 = cvtpk(pf[10], pf[11]);
      u32 cv6 = cvtpk(pf[12], pf[13]), cv7 = cvtpk(pf[14], pf[15]);
      u32x2 s0 = pswap(cv0, cv2);
      u32x2 s1 = pswap(cv1, cv3);
      u32x2 s2 = pswap(cv4, cv6);
      u32x2 s3 = pswap(cv5, cv7);
      u32x4 pa0u = {s0.x, s1.x, s0.y, s1.y};
      u32x4 pa1u = {s2.x, s3.x, s2.y, s3.y};
      bf16x8 pa0 = __builtin_bit_cast(bf16x8, pa0u);
      bf16x8 pa1 = __builtin_bit_cast(bf16x8, pa1u);
      __builtin_amdgcn_s_setprio(1);
      y0 = mfma32(pa0, vc[0], y0);
      y0 = mfma32(pa1, vc[4], y0);
      y1 = mfma32(pa0, vc[1], y1);
      y1 = mfma32(pa1, vc[5], y1);
      y2 = mfma32(pa0, vc[2], y2);
      y2 = mfma32(pa1, vc[6], y2);
      y3 = mfma32(pa0, vc[3], y3);
      y3 = mfma32(pa1, vc[7], y3);
      __builtin_amdgcn_s_setprio(0);
    };

    int NT = 2 * qblk + 2;   // even
    issue(0, 0);
    vload(vA, 0);
    __syncthreads();
    for (int t = 0; t < NT; t += 2) {
      int k0 = t * 64;
      issue(k0 + 64, 1);                       // K(t+1) -> Klds[1]
      tilecomp(0, k0, vA, vB, k0 + 64);        // issues V(t+1) -> vB
      __syncthreads();
      int k1 = k0 + 64;
      bool more = (t + 2 < NT);
      if (more) issue(k1 + 64, 0);             // K(t+2) -> Klds[0]
      tilecomp(1, k1, vB, vA, more ? k1 + 64 : k1);  // issues V(t+2) -> vA
      __syncthreads();
    }

    // rs: combine the two h5 key-subsets (same q)
    rs += __shfl_xor(rs, 32, 64);

    // key-half combine via Scr, two qr-parity phases (16KB per qr)
#pragma unroll
    for (int pr = 0; pr < 2; ++pr) {
      float* scr = Scr + (qr >> 1) * 4096;
      if ((qr & 1) == pr && kh == 1) {
#pragma unroll
        for (int db = 0; db < 4; ++db) {
          const f32x16& yv = (db == 0) ? y0 : (db == 1) ? y1 : (db == 2) ? y2 : y3;
#pragma unroll
          for (int r4 = 0; r4 < 4; ++r4) {
            f32x4 ch = {yv[r4 * 4 + 0], yv[r4 * 4 + 1], yv[r4 * 4 + 2], yv[r4 * 4 + 3]};
            *(f32x4*)&scr[((db * 4 + r4) * 64 + lane) * 4] = ch;
          }
        }
        if (lane < 32) rsbuf[1][qr][lane] = rs;
      }
      __syncthreads();
      if ((qr & 1) == pr && kh == 0) {
        float rs2 = rs + rsbuf[1][qr][l31];
        float inv = 1.0f / rs2;
        if (lane < 32) rsbuf[0][qr][lane] = inv;
#pragma unroll
        for (int db = 0; db < 4; ++db) {
          f32x16& yv = (db == 0) ? y0 : (db == 1) ? y1 : (db == 2) ? y2 : y3;
#pragma unroll
          for (int r4 = 0; r4 < 4; ++r4) {
            f32x4 ch = *(const f32x4*)&scr[((db * 4 + r4) * 64 + lane) * 4];
#pragma unroll
            for (int k = 0; k < 4; ++k) yv[r4 * 4 + k] += ch[k];
          }
        }
        u16* Yp = Yb + ((size_t)b * S_LEN + qw) * (NHEAD * DHEAD) + h * DHEAD;
#pragma unroll
        for (int db = 0; db < 4; ++db) {
          const f32x16& yv = (db == 0) ? y0 : (db == 1) ? y1 : (db == 2) ? y2 : y3;
#pragma unroll
          for (int reg = 0; reg < 16; ++reg) {
            int qp2 = (reg & 3) + 8 * (reg >> 2) + 4 * h5;
            float rv = rsbuf[0][qr][qp2];
            Yp[(size_t)qp2 * (NHEAD * DHEAD) + db * 32 + l31] = f2b(yv[reg] * rv);
          }
        }
      }
      __syncthreads();
    }
  };

  runSeg(31 - qpj);   // long segment first
  runSeg(qpj);        // complementary short: 68 tiles for every block, flat
}

// ---------------- output projection: 4 waves/block ----------------
__global__ __launch_bounds__(256) void k_oproj(const u16* __restrict__ Yb,
                                               const u16* __restrict__ WoB,
                                               float* __restrict__ out) {
  int wid = threadIdx.x >> 6;
  int lane = threadIdx.x & 63;
  int mb = (blockIdx.x * 4 + wid) * 32 + blockIdx.y * 16;
  int nb = blockIdx.z * 64;
  int row16 = lane & 15, kgrp = lane >> 4;
  f32x4 acc[4];
#pragma unroll
  for (int nc = 0; nc < 4; ++nc) acc[nc] = zero4();
#pragma unroll 4
  for (int kc = 0; kc < 32; ++kc) {
    bf16x8 a0 = *(const bf16x8*)(Yb + (size_t)(mb + row16) * 1024 + kc * 32 + kgrp * 8);
#pragma unroll
    for (int nc = 0; nc < 4; ++nc) {
      bf16x8 bw =
          *(const bf16x8*)(WoB + (size_t)(nb + nc * 16 + row16) * 1024 + kc * 32 + kgrp * 8);
      acc[nc] = mfma16(a0, bw, acc[nc]);
    }
  }
#pragma unroll
  for (int nc = 0; nc < 4; ++nc)
#pragma unroll
    for (int i = 0; i < 4; ++i)
      out[(size_t)(mb + kgrp * 4 + i) * DHEAD + nb + nc * 16 + row16] = acc[nc][i];
}

extern "C" void kernel_launch(void* const* d_in, const int* in_sizes, int n_in,
                              void* d_out, int out_size, void* d_ws, size_t ws_size,
                              hipStream_t stream) {
  const float* x = (const float*)d_in[0];
  const float* Wq = (const float*)d_in[1];
  const float* Wk = (const float*)d_in[2];
  const float* Wo = (const float*)d_in[3];
  float* out = (float*)d_out;

  char* ws = (char*)d_ws;
  size_t off = 0;
  auto alloc = [&](size_t bytes) -> void* {
    void* p = ws + off;
    off += (bytes + 255) & ~(size_t)255;
    return p;
  };
  const size_t nx = (size_t)NBATCH * S_LEN * DHEAD;
  const size_t nqk = (size_t)NBATCH * NHEAD * S_LEN * DHEAD;
  u16* xb = (u16*)alloc(nx * 2);
  u16* VbF = (u16*)alloc(nx * 2);
  u16* Wqt = (u16*)alloc((size_t)NHEAD * DHEAD * DHEAD * 2);
  u16* Wkt = (u16*)alloc((size_t)NHEAD * DHEAD * DHEAD * 2);
  u16* WoB = (u16*)alloc((size_t)DHEAD * NHEAD * DHEAD * 2);
  u16* Qb = (u16*)alloc(nqk * 2);
  u16* KbF = (u16*)alloc(nqk * 2);
  u16* Yb = (u16*)alloc(nqk * 2);
  (void)ws_size;

  k_conv_x<<<dim3(nx / 256), dim3(256), 0, stream>>>(x, xb, VbF);
  k_conv_w<<<dim3(131072 / 256), dim3(256), 0, stream>>>(Wq, Wk, Wo, Wqt, Wkt, WoB);
  k_proj<<<dim3(S_LEN / 32 / 4, NHEAD, 2 * NBATCH), dim3(256), 0, stream>>>(xb, Wqt, Wkt, Qb, KbF);
  k_attn<<<dim3(256), dim3(512), 0, stream>>>(Qb, KbF, VbF, Yb);
  k_oproj<<<dim3((NBATCH * S_LEN) / 32 / 4, 2, 2), dim3(256), 0, stream>>>(Yb, WoB, out);
}

// Round 17
// 145.874 us; speedup vs baseline: 1.3459x; 1.0858x over previous
//
#include <hip/hip_runtime.h>
#include <hip/hip_bf16.h>

typedef unsigned short u16;
typedef unsigned int u32;
typedef __attribute__((ext_vector_type(8))) short bf16x8;
typedef __attribute__((ext_vector_type(4))) float f32x4;
typedef __attribute__((ext_vector_type(16))) float f32x16;
typedef __attribute__((ext_vector_type(2))) unsigned int u32x2;
typedef __attribute__((ext_vector_type(4))) unsigned int u32x4;

#define S_LEN 4096
#define DHEAD 128
#define NHEAD 8
#define NBATCH 2

__device__ __forceinline__ u16 f2b(float f) {
  __hip_bfloat16 h = __float2bfloat16(f);
  return *(u16*)&h;
}

__device__ __forceinline__ f32x4 mfma16(bf16x8 a, bf16x8 b, f32x4 c) {
  return __builtin_amdgcn_mfma_f32_16x16x32_bf16(a, b, c, 0, 0, 0);
}
__device__ __forceinline__ f32x16 mfma32(bf16x8 a, bf16x8 b, f32x16 c) {
  return __builtin_amdgcn_mfma_f32_32x32x16_bf16(a, b, c, 0, 0, 0);
}

__device__ __forceinline__ f32x4 zero4() { f32x4 z = {0.f, 0.f, 0.f, 0.f}; return z; }

__device__ __forceinline__ u32 cvtpk(float lo, float hi) {
  u32 r;
  asm("v_cvt_pk_bf16_f32 %0, %1, %2" : "=v"(r) : "v"(lo), "v"(hi));
  return r;
}
__device__ __forceinline__ u32x2 pswap(u32 a, u32 b) {
  return __builtin_amdgcn_permlane32_swap(a, b, false, false);
}

// async global->LDS, 16B/lane; LDS dest = wave-uniform base + lane*16
__device__ __forceinline__ void gll16(const u16* g, u16* l) {
  __builtin_amdgcn_global_load_lds(
      (const __attribute__((address_space(1))) u32*)g,
      (__attribute__((address_space(3))) u32*)l, 16, 0, 0);
}

// ---------------- converts ----------------
// xb row-major bf16; VbF: V in 32x32-MFMA B-fragment order.
// VbF frag g = kh*8 + m2*4 + db at [((b*64+t64)*16+g)*512 + l*8 + j]:
//   key = t64*64+kh*32+m2*16+(l>>5)*8+j, dout = db*32+(l&31)
__global__ void k_conv_x(const float* __restrict__ x, u16* __restrict__ xb,
                         u16* __restrict__ VbF) {
  int idx = blockIdx.x * blockDim.x + threadIdx.x;
  float v = x[idx];
  u16 bv = f2b(v);
  xb[idx] = bv;
  int d = idx & 127;
  int bs = idx >> 7;
  int b = bs >> 12;
  int s = bs & 4095;  // key
  int t64 = s >> 6, kh = (s >> 5) & 1, m2 = (s >> 4) & 1;
  int h5v = (s >> 3) & 1, j = s & 7;
  int db = d >> 5;
  int l = (d & 31) + 32 * h5v;
  int g = kh * 8 + m2 * 4 + db;
  VbF[(((size_t)b * 64 + t64) * 16 + g) * 512 + l * 8 + j] = bv;
}

__global__ void k_conv_w(const float* __restrict__ Wq, const float* __restrict__ Wk,
                         const float* __restrict__ Wo, u16* __restrict__ Wqt,
                         u16* __restrict__ Wkt, u16* __restrict__ WoB) {
  int idx = blockIdx.x * blockDim.x + threadIdx.x;
  int h = idx >> 14;
  int d = (idx >> 7) & 127;
  int e = idx & 127;
  int t = (h << 14) + (e << 7) + d;
  Wqt[t] = f2b(Wq[idx]);
  Wkt[t] = f2b(Wk[idx]);
  WoB[idx] = f2b(Wo[idx]);
}

// ---------------- Q/K projection: 4 waves/block ----------------
// Q -> row-major Qb; K -> KbF fragment order: frag f = kh*8+m at
// [((bh*64+t64)*16+f)*512 + l*8 + j]: key=t64*64+kh*32+(l&31), d=m*16+(l>>5)*8+j
__global__ __launch_bounds__(256) void k_proj(const u16* __restrict__ xb,
                                              const u16* __restrict__ Wqt,
                                              const u16* __restrict__ Wkt,
                                              u16* __restrict__ Qb, u16* __restrict__ KbF) {
  int wid = threadIdx.x >> 6;
  int lane = threadIdx.x & 63;
  int qt = blockIdx.x * 4 + wid;
  int h = blockIdx.y, z = blockIdx.z;
  int b = z >> 1, w = z & 1;
  int bh = b * NHEAD + h;
  int row16 = lane & 15, kgrp = lane >> 4;
  int sb = qt * 32;
  const u16* xp = xb + ((size_t)b * S_LEN + sb) * DHEAD;
  bf16x8 a[2][4];
#pragma unroll
  for (int r = 0; r < 2; ++r)
#pragma unroll
    for (int kc = 0; kc < 4; ++kc)
      a[r][kc] = *(const bf16x8*)(xp + (r * 16 + row16) * DHEAD + kc * 32 + kgrp * 8);

  const u16* Wt = (w == 0 ? Wqt : Wkt) + (size_t)h * DHEAD * DHEAD;
  f32x4 acc[2][8];
#pragma unroll
  for (int r = 0; r < 2; ++r)
#pragma unroll
    for (int nc = 0; nc < 8; ++nc) acc[r][nc] = zero4();
#pragma unroll
  for (int kc = 0; kc < 4; ++kc)
#pragma unroll
    for (int nc = 0; nc < 8; ++nc) {
      bf16x8 bw = *(const bf16x8*)(Wt + (nc * 16 + row16) * DHEAD + kc * 32 + kgrp * 8);
      acc[0][nc] = mfma16(a[0][kc], bw, acc[0][nc]);
      acc[1][nc] = mfma16(a[1][kc], bw, acc[1][nc]);
    }
  if (w == 0) {
    u16* Out = Qb + ((size_t)bh * S_LEN + sb) * DHEAD;
#pragma unroll
    for (int r = 0; r < 2; ++r)
#pragma unroll
      for (int nc = 0; nc < 8; ++nc)
#pragma unroll
        for (int i = 0; i < 4; ++i)
          Out[(size_t)(r * 16 + kgrp * 4 + i) * DHEAD + nc * 16 + row16] =
              f2b(acc[r][nc][i]);
  } else {
#pragma unroll
    for (int r = 0; r < 2; ++r)
#pragma unroll
      for (int nc = 0; nc < 8; ++nc)
#pragma unroll
        for (int i = 0; i < 4; ++i) {
          int key = sb + r * 16 + kgrp * 4 + i;
          int e = nc * 16 + row16;
          int t64 = key >> 6, kh = (key >> 5) & 1;
          int m = e >> 4;
          int l = (key & 31) + 32 * ((e >> 3) & 1);
          int j = e & 7;
          int f = kh * 8 + m;
          KbF[(((size_t)bh * 64 + t64) * 16 + f) * 512 + l * 8 + j] = f2b(acc[r][nc][i]);
        }
  }
}

// ---------------- causal flash attention: 4-deep K + 1 barrier / 2 tiles -----
// QBLK=128, 8 waves = 4 qr x 2 kh, balanced pairs {j,31-j}, 68 tiles, flat.
// K staged 4-deep in LDS (64KB) -> ONE barrier per TWO tiles: waves drift
// across a ~2-tile window so LDS/vmem phases of some waves overlap MFMA/VALU
// of others (breaks the barrier convoy). V in registers (dbuf). Combine
// scratch aliases the dead K LDS -> single-phase combine.
__global__ __launch_bounds__(512) void k_attn(const u16* __restrict__ Qb,
                                              const u16* __restrict__ KbF,
                                              const u16* __restrict__ VbF,
                                              u16* __restrict__ Yb) {
  int p = blockIdx.x;                      // 0..255
  int xcd = p & 7;
  int j2 = p >> 3;                         // 0..31
  int bh = xcd + (j2 >= 16 ? 8 : 0);       // 0..15 (same (b,h) per XCD)
  int qpj = j2 & 15;
  int b = bh >> 3, h = bh & 7;

  int tid = threadIdx.x;
  int wid = tid >> 6;                      // 0..7
  int lane = tid & 63;
  int qr = wid >> 1;                       // 0..3 (32 q-rows each)
  int kh = wid & 1;                        // key half of 64-key tile
  int l31 = lane & 31, h5 = lane >> 5;

  __shared__ __align__(16) u16 SMEM[4][8192];   // 64 KB: K 4-deep / combine scr
  __shared__ float rsbuf[2][4][32];             // 1 KB

  const u16* Kbase = KbF + (size_t)bh * 64 * 16 * 512;
  const u16* Vbase = VbF + (size_t)b * 64 * 16 * 512;

  // stage one 64-key K tile: 16 frags (1KB contiguous each), 2 gll per wave
  auto issue = [&](int k0, int buf) {
    const u16* Ks = Kbase + (size_t)(k0 >> 6) * 16 * 512;
#pragma unroll
    for (int fi = 0; fi < 2; ++fi) {
      int f = wid * 2 + fi;
      gll16(Ks + f * 512 + lane * 8, &SMEM[buf][f * 512]);
    }
  };
  // V frags straight to registers (this wave's kh half: 8 frags, 1KB/instr)
  auto vload = [&](bf16x8 (&dst)[8], int k0) {
    const u16* Vs = Vbase + ((size_t)(k0 >> 6) * 16 + kh * 8) * 512 + lane * 8;
#pragma unroll
    for (int g = 0; g < 8; ++g) dst[g] = *(const bf16x8*)(Vs + g * 512);
  };

  const float c2 = 0.12754274816295166f;    // (1/sqrt(128)) * log2(e)
  const float clip2 = 14.426950408889634f;  // 10 * log2(e)

  auto runSeg = [&](int qblk) {
    int qb0 = qblk * 128;
    int qw = qb0 + qr * 32;
    int qrow = qw + l31;                   // this lane's q-row
    const u16* Qp = Qb + ((size_t)bh * S_LEN + qw) * DHEAD;

    bf16x8 bq[8];
#pragma unroll
    for (int m = 0; m < 8; ++m)
      bq[m] = *(const bf16x8*)(Qp + (size_t)l31 * DHEAD + m * 16 + h5 * 8);

    f32x16 y0, y1, y2, y3;
#pragma unroll
    for (int i = 0; i < 16; ++i) { y0[i] = 0.f; y1[i] = 0.f; y2[i] = 0.f; y3[i] = 0.f; }
    float rs = 0.f;

    bf16x8 vA[8], vB[8];

    auto tilecomp = [&](int buf, int k0, bf16x8 (&vc)[8]) {
      // QK^T swapped: S[key][q]
      f32x16 sc;
#pragma unroll
      for (int i = 0; i < 16; ++i) sc[i] = 0.f;
      __builtin_amdgcn_s_setprio(1);
#pragma unroll
      for (int m = 0; m < 8; ++m) {
        bf16x8 kf = *(const bf16x8*)&SMEM[buf][((kh * 8 + m) * 512) + lane * 8];
        sc = mfma32(kf, bq[m], sc);
      }
      __builtin_amdgcn_s_setprio(0);

      // per-lane softmax: all 16 scores belong to q = l31
      float pf[16];
      int kb = k0 + kh * 32 + h5 * 4;
      bool nomask = (k0 + kh * 32 + 31) <= qw;   // wave-uniform
      if (nomask) {
#pragma unroll
        for (int reg = 0; reg < 16; ++reg) {
          float v = __builtin_amdgcn_fmed3f(sc[reg] * c2, -clip2, clip2);
          float pc = __builtin_amdgcn_exp2f(v);
          rs += pc;
          pf[reg] = pc;
        }
      } else {
#pragma unroll
        for (int reg = 0; reg < 16; ++reg) {
          int key = kb + (reg & 3) + 8 * (reg >> 2);
          float v = __builtin_amdgcn_fmed3f(sc[reg] * c2, -clip2, clip2);
          float pc = __builtin_amdgcn_exp2f(v);
          pc = (key > qrow) ? 0.0f : pc;
          rs += pc;
          pf[reg] = pc;
        }
      }
      // pack P -> PV A-fragments
      u32 cv0 = cvtpk(pf[0], pf[1]), cv1 = cvtpk(pf[2], pf[3]);
      u32 cv2 = cvtpk(pf[4], pf[5]), cv3 = cvtpk(pf[6], pf[7]);
      u32 cv4 = cvtpk(pf[8], pf[9]), cv5 = cvtpk(pf[10], pf[11]);
      u32 cv6 = cvtpk(pf[12], pf[13]), cv7 = cvtpk(pf[14], pf[15]);
      u32x2 s0 = pswap(cv0, cv2);
      u32x2 s1 = pswap(cv1, cv3);
      u32x2 s2 = pswap(cv4, cv6);
      u32x2 s3 = pswap(cv5, cv7);
      u32x4 pa0u = {s0.x, s1.x, s0.y, s1.y};
      u32x4 pa1u = {s2.x, s3.x, s2.y, s3.y};
      bf16x8 pa0 = __builtin_bit_cast(bf16x8, pa0u);
      bf16x8 pa1 = __builtin_bit_cast(bf16x8, pa1u);
      __builtin_amdgcn_s_setprio(1);
      y0 = mfma32(pa0, vc[0], y0);
      y0 = mfma32(pa1, vc[4], y0);
      y1 = mfma32(pa0, vc[1], y1);
      y1 = mfma32(pa1, vc[5], y1);
      y2 = mfma32(pa0, vc[2], y2);
      y2 = mfma32(pa1, vc[6], y2);
      y3 = mfma32(pa0, vc[3], y3);
      y3 = mfma32(pa1, vc[7], y3);
      __builtin_amdgcn_s_setprio(0);
    };

    int NT = 2 * qblk + 2;   // even
    issue(0, 0);
    issue(64, 1);
    vload(vA, 0);
    __syncthreads();
    for (int t = 0; t < NT; t += 2) {
      int k0 = t * 64;
      vload(vB, k0 + 64);                       // V(t+1): covered by tile t
      if (t + 2 < NT) issue(k0 + 128, (t + 2) & 3);  // bufs freed by last barrier
      if (t + 3 < NT) issue(k0 + 192, (t + 3) & 3);
      tilecomp(t & 3, k0, vA);
      if (t + 2 < NT) vload(vA, k0 + 128);      // V(t+2): covered by tile t+1
      tilecomp((t + 1) & 3, k0 + 64, vB);
      __syncthreads();   // one barrier per TWO tiles: 2-tile drift window
    }

    // rs: combine the two h5 key-subsets (same q)
    rs += __shfl_xor(rs, 32, 64);

    // key-half combine through the dead K LDS: 16KB scratch per qr group
    float* scr = (float*)&SMEM[0][0] + qr * 4096;
    if (kh == 1) {
#pragma unroll
      for (int db = 0; db < 4; ++db) {
        const f32x16& yv = (db == 0) ? y0 : (db == 1) ? y1 : (db == 2) ? y2 : y3;
#pragma unroll
        for (int r4 = 0; r4 < 4; ++r4) {
          f32x4 ch = {yv[r4 * 4 + 0], yv[r4 * 4 + 1], yv[r4 * 4 + 2], yv[r4 * 4 + 3]};
          *(f32x4*)&scr[((db * 4 + r4) * 64 + lane) * 4] = ch;
        }
      }
      if (lane < 32) rsbuf[1][qr][lane] = rs;
    }
    __syncthreads();
    if (kh == 0) {
      float rs2 = rs + rsbuf[1][qr][l31];
      float inv = 1.0f / rs2;
      if (lane < 32) rsbuf[0][qr][lane] = inv;
#pragma unroll
      for (int db = 0; db < 4; ++db) {
        f32x16& yv = (db == 0) ? y0 : (db == 1) ? y1 : (db == 2) ? y2 : y3;
#pragma unroll
        for (int r4 = 0; r4 < 4; ++r4) {
          f32x4 ch = *(const f32x4*)&scr[((db * 4 + r4) * 64 + lane) * 4];
#pragma unroll
          for (int k = 0; k < 4; ++k) yv[r4 * 4 + k] += ch[k];
        }
      }
      u16* Yp = Yb + ((size_t)b * S_LEN + qw) * (NHEAD * DHEAD) + h * DHEAD;
#pragma unroll
      for (int db = 0; db < 4; ++db) {
        const f32x16& yv = (db == 0) ? y0 : (db == 1) ? y1 : (db == 2) ? y2 : y3;
#pragma unroll
        for (int reg = 0; reg < 16; ++reg) {
          int qp2 = (reg & 3) + 8 * (reg >> 2) + 4 * h5;
          float rv = rsbuf[0][qr][qp2];
          Yp[(size_t)qp2 * (NHEAD * DHEAD) + db * 32 + l31] = f2b(yv[reg] * rv);
        }
      }
    }
    __syncthreads();  // scratch + rsbuf reads done before next segment stages
  };

  runSeg(31 - qpj);   // long segment first
  runSeg(qpj);        // complementary short: 68 tiles for every block, flat
}

// ---------------- output projection: 4 waves/block ----------------
__global__ __launch_bounds__(256) void k_oproj(const u16* __restrict__ Yb,
                                               const u16* __restrict__ WoB,
                                               float* __restrict__ out) {
  int wid = threadIdx.x >> 6;
  int lane = threadIdx.x & 63;
  int mb = (blockIdx.x * 4 + wid) * 32 + blockIdx.y * 16;
  int nb = blockIdx.z * 64;
  int row16 = lane & 15, kgrp = lane >> 4;
  f32x4 acc[4];
#pragma unroll
  for (int nc = 0; nc < 4; ++nc) acc[nc] = zero4();
#pragma unroll 4
  for (int kc = 0; kc < 32; ++kc) {
    bf16x8 a0 = *(const bf16x8*)(Yb + (size_t)(mb + row16) * 1024 + kc * 32 + kgrp * 8);
#pragma unroll
    for (int nc = 0; nc < 4; ++nc) {
      bf16x8 bw =
          *(const bf16x8*)(WoB + (size_t)(nb + nc * 16 + row16) * 1024 + kc * 32 + kgrp * 8);
      acc[nc] = mfma16(a0, bw, acc[nc]);
    }
  }
#pragma unroll
  for (int nc = 0; nc < 4; ++nc)
#pragma unroll
    for (int i = 0; i < 4; ++i)
      out[(size_t)(mb + kgrp * 4 + i) * DHEAD + nb + nc * 16 + row16] = acc[nc][i];
}

extern "C" void kernel_launch(void* const* d_in, const int* in_sizes, int n_in,
                              void* d_out, int out_size, void* d_ws, size_t ws_size,
                              hipStream_t stream) {
  const float* x = (const float*)d_in[0];
  const float* Wq = (const float*)d_in[1];
  const float* Wk = (const float*)d_in[2];
  const float* Wo = (const float*)d_in[3];
  float* out = (float*)d_out;

  char* ws = (char*)d_ws;
  size_t off = 0;
  auto alloc = [&](size_t bytes) -> void* {
    void* p = ws + off;
    off += (bytes + 255) & ~(size_t)255;
    return p;
  };
  const size_t nx = (size_t)NBATCH * S_LEN * DHEAD;
  const size_t nqk = (size_t)NBATCH * NHEAD * S_LEN * DHEAD;
  u16* xb = (u16*)alloc(nx * 2);
  u16* VbF = (u16*)alloc(nx * 2);
  u16* Wqt = (u16*)alloc((size_t)NHEAD * DHEAD * DHEAD * 2);
  u16* Wkt = (u16*)alloc((size_t)NHEAD * DHEAD * DHEAD * 2);
  u16* WoB = (u16*)alloc((size_t)DHEAD * NHEAD * DHEAD * 2);
  u16* Qb = (u16*)alloc(nqk * 2);
  u16* KbF = (u16*)alloc(nqk * 2);
  u16* Yb = (u16*)alloc(nqk * 2);
  (void)ws_size;

  k_conv_x<<<dim3(nx / 256), dim3(256), 0, stream>>>(x, xb, VbF);
  k_conv_w<<<dim3(131072 / 256), dim3(256), 0, stream>>>(Wq, Wk, Wo, Wqt, Wkt, WoB);
  k_proj<<<dim3(S_LEN / 32 / 4, NHEAD, 2 * NBATCH), dim3(256), 0, stream>>>(xb, Wqt, Wkt, Qb, KbF);
  k_attn<<<dim3(256), dim3(512), 0, stream>>>(Qb, KbF, VbF, Yb);
  k_oproj<<<dim3((NBATCH * S_LEN) / 32 / 4, 2, 2), dim3(256), 0, stream>>>(Yb, WoB, out);
}

// Round 18
// 144.286 us; speedup vs baseline: 1.3608x; 1.0110x over previous
//
#include <hip/hip_runtime.h>
#include <hip/hip_bf16.h>

typedef unsigned short u16;
typedef unsigned int u32;
typedef __attribute__((ext_vector_type(8))) short bf16x8;
typedef __attribute__((ext_vector_type(4))) float f32x4;
typedef __attribute__((ext_vector_type(16))) float f32x16;
typedef __attribute__((ext_vector_type(2))) unsigned int u32x2;
typedef __attribute__((ext_vector_type(4))) unsigned int u32x4;

#define S_LEN 4096
#define DHEAD 128
#define NHEAD 8
#define NBATCH 2

__device__ __forceinline__ u16 f2b(float f) {
  __hip_bfloat16 h = __float2bfloat16(f);
  return *(u16*)&h;
}

__device__ __forceinline__ f32x4 mfma16(bf16x8 a, bf16x8 b, f32x4 c) {
  return __builtin_amdgcn_mfma_f32_16x16x32_bf16(a, b, c, 0, 0, 0);
}
__device__ __forceinline__ f32x16 mfma32(bf16x8 a, bf16x8 b, f32x16 c) {
  return __builtin_amdgcn_mfma_f32_32x32x16_bf16(a, b, c, 0, 0, 0);
}

__device__ __forceinline__ f32x4 zero4() { f32x4 z = {0.f, 0.f, 0.f, 0.f}; return z; }

__device__ __forceinline__ u32 cvtpk(float lo, float hi) {
  u32 r;
  asm("v_cvt_pk_bf16_f32 %0, %1, %2" : "=v"(r) : "v"(lo), "v"(hi));
  return r;
}
__device__ __forceinline__ u32x2 pswap(u32 a, u32 b) {
  return __builtin_amdgcn_permlane32_swap(a, b, false, false);
}

// async global->LDS, 16B/lane; LDS dest = wave-uniform base + lane*16
__device__ __forceinline__ void gll16(const u16* g, u16* l) {
  __builtin_amdgcn_global_load_lds(
      (const __attribute__((address_space(1))) u32*)g,
      (__attribute__((address_space(3))) u32*)l, 16, 0, 0);
}

// ---------------- converts ----------------
// xb row-major bf16; VbF: V in 32x32-MFMA B-fragment order.
// VbF frag g = kh*8 + m2*4 + db at [((b*64+t64)*16+g)*512 + l*8 + j]:
//   key = t64*64+kh*32+m2*16+(l>>5)*8+j, dout = db*32+(l&31)
__global__ void k_conv_x(const float* __restrict__ x, u16* __restrict__ xb,
                         u16* __restrict__ VbF) {
  int idx = blockIdx.x * blockDim.x + threadIdx.x;
  float v = x[idx];
  u16 bv = f2b(v);
  xb[idx] = bv;
  int d = idx & 127;
  int bs = idx >> 7;
  int b = bs >> 12;
  int s = bs & 4095;  // key
  int t64 = s >> 6, kh = (s >> 5) & 1, m2 = (s >> 4) & 1;
  int h5v = (s >> 3) & 1, j = s & 7;
  int db = d >> 5;
  int l = (d & 31) + 32 * h5v;
  int g = kh * 8 + m2 * 4 + db;
  VbF[(((size_t)b * 64 + t64) * 16 + g) * 512 + l * 8 + j] = bv;
}

__global__ void k_conv_w(const float* __restrict__ Wq, const float* __restrict__ Wk,
                         const float* __restrict__ Wo, u16* __restrict__ Wqt,
                         u16* __restrict__ Wkt, u16* __restrict__ WoB) {
  int idx = blockIdx.x * blockDim.x + threadIdx.x;
  int h = idx >> 14;
  int d = (idx >> 7) & 127;
  int e = idx & 127;
  int t = (h << 14) + (e << 7) + d;
  Wqt[t] = f2b(Wq[idx]);
  Wkt[t] = f2b(Wk[idx]);
  WoB[idx] = f2b(Wo[idx]);
}

// ---------------- Q/K projection: 4 waves/block ----------------
// Q -> row-major Qb; K -> KbF fragment order: frag f = kh*8+m at
// [((bh*64+t64)*16+f)*512 + l*8 + j]: key=t64*64+kh*32+(l&31), d=m*16+(l>>5)*8+j
__global__ __launch_bounds__(256) void k_proj(const u16* __restrict__ xb,
                                              const u16* __restrict__ Wqt,
                                              const u16* __restrict__ Wkt,
                                              u16* __restrict__ Qb, u16* __restrict__ KbF) {
  int wid = threadIdx.x >> 6;
  int lane = threadIdx.x & 63;
  int qt = blockIdx.x * 4 + wid;
  int h = blockIdx.y, z = blockIdx.z;
  int b = z >> 1, w = z & 1;
  int bh = b * NHEAD + h;
  int row16 = lane & 15, kgrp = lane >> 4;
  int sb = qt * 32;
  const u16* xp = xb + ((size_t)b * S_LEN + sb) * DHEAD;
  bf16x8 a[2][4];
#pragma unroll
  for (int r = 0; r < 2; ++r)
#pragma unroll
    for (int kc = 0; kc < 4; ++kc)
      a[r][kc] = *(const bf16x8*)(xp + (r * 16 + row16) * DHEAD + kc * 32 + kgrp * 8);

  const u16* Wt = (w == 0 ? Wqt : Wkt) + (size_t)h * DHEAD * DHEAD;
  f32x4 acc[2][8];
#pragma unroll
  for (int r = 0; r < 2; ++r)
#pragma unroll
    for (int nc = 0; nc < 8; ++nc) acc[r][nc] = zero4();
#pragma unroll
  for (int kc = 0; kc < 4; ++kc)
#pragma unroll
    for (int nc = 0; nc < 8; ++nc) {
      bf16x8 bw = *(const bf16x8*)(Wt + (nc * 16 + row16) * DHEAD + kc * 32 + kgrp * 8);
      acc[0][nc] = mfma16(a[0][kc], bw, acc[0][nc]);
      acc[1][nc] = mfma16(a[1][kc], bw, acc[1][nc]);
    }
  if (w == 0) {
    u16* Out = Qb + ((size_t)bh * S_LEN + sb) * DHEAD;
#pragma unroll
    for (int r = 0; r < 2; ++r)
#pragma unroll
      for (int nc = 0; nc < 8; ++nc)
#pragma unroll
        for (int i = 0; i < 4; ++i)
          Out[(size_t)(r * 16 + kgrp * 4 + i) * DHEAD + nc * 16 + row16] =
              f2b(acc[r][nc][i]);
  } else {
#pragma unroll
    for (int r = 0; r < 2; ++r)
#pragma unroll
      for (int nc = 0; nc < 8; ++nc)
#pragma unroll
        for (int i = 0; i < 4; ++i) {
          int key = sb + r * 16 + kgrp * 4 + i;
          int e = nc * 16 + row16;
          int t64 = key >> 6, kh = (key >> 5) & 1;
          int m = e >> 4;
          int l = (key & 31) + 32 * ((e >> 3) & 1);
          int j = e & 7;
          int f = kh * 8 + m;
          KbF[(((size_t)bh * 64 + t64) * 16 + f) * 512 + l * 8 + j] = f2b(acc[r][nc][i]);
        }
  }
}

// ---------------- causal flash attention: counted-vmcnt barrier (T4) ---------
// r17 frame (4-deep K, 1 barrier / 2 tiles) but the loop barrier is now
// s_waitcnt vmcnt(8) + raw s_barrier: drains exactly the 4 K-glls (cross-wave
// LDS visibility) while the 8 vA register prefetches stay in flight across
// the barrier. Program order pinned with sched_barrier(0) (rules #18/#21).
__global__ __launch_bounds__(512) void k_attn(const u16* __restrict__ Qb,
                                              const u16* __restrict__ KbF,
                                              const u16* __restrict__ VbF,
                                              u16* __restrict__ Yb) {
  int p = blockIdx.x;                      // 0..255
  int xcd = p & 7;
  int j2 = p >> 3;                         // 0..31
  int bh = xcd + (j2 >= 16 ? 8 : 0);       // 0..15 (same (b,h) per XCD)
  int qpj = j2 & 15;
  int b = bh >> 3, h = bh & 7;

  int tid = threadIdx.x;
  int wid = tid >> 6;                      // 0..7
  int lane = tid & 63;
  int qr = wid >> 1;                       // 0..3 (32 q-rows each)
  int kh = wid & 1;                        // key half of 64-key tile
  int l31 = lane & 31, h5 = lane >> 5;

  __shared__ __align__(16) u16 SMEM[4][8192];   // 64 KB: K 4-deep / combine scr
  __shared__ float rsbuf[2][4][32];             // 1 KB

  const u16* Kbase = KbF + (size_t)bh * 64 * 16 * 512;
  const u16* Vbase = VbF + (size_t)b * 64 * 16 * 512;

  // stage one 64-key K tile: 16 frags (1KB contiguous each), 2 gll per wave
  auto issue = [&](int k0, int buf) {
    const u16* Ks = Kbase + (size_t)(k0 >> 6) * 16 * 512;
#pragma unroll
    for (int fi = 0; fi < 2; ++fi) {
      int f = wid * 2 + fi;
      gll16(Ks + f * 512 + lane * 8, &SMEM[buf][f * 512]);
    }
  };
  // V frags straight to registers (this wave's kh half: 8 frags, 1KB/instr)
  auto vload = [&](bf16x8 (&dst)[8], int k0) {
    const u16* Vs = Vbase + ((size_t)(k0 >> 6) * 16 + kh * 8) * 512 + lane * 8;
#pragma unroll
    for (int g = 0; g < 8; ++g) dst[g] = *(const bf16x8*)(Vs + g * 512);
  };

  const float c2 = 0.12754274816295166f;    // (1/sqrt(128)) * log2(e)
  const float clip2 = 14.426950408889634f;  // 10 * log2(e)

  auto runSeg = [&](int qblk) {
    int qb0 = qblk * 128;
    int qw = qb0 + qr * 32;
    int qrow = qw + l31;                   // this lane's q-row
    const u16* Qp = Qb + ((size_t)bh * S_LEN + qw) * DHEAD;

    bf16x8 bq[8];
#pragma unroll
    for (int m = 0; m < 8; ++m)
      bq[m] = *(const bf16x8*)(Qp + (size_t)l31 * DHEAD + m * 16 + h5 * 8);

    f32x16 y0, y1, y2, y3;
#pragma unroll
    for (int i = 0; i < 16; ++i) { y0[i] = 0.f; y1[i] = 0.f; y2[i] = 0.f; y3[i] = 0.f; }
    float rs = 0.f;

    bf16x8 vA[8], vB[8];

    auto tilecomp = [&](int buf, int k0, bf16x8 (&vc)[8]) {
      // QK^T swapped: S[key][q]
      f32x16 sc;
#pragma unroll
      for (int i = 0; i < 16; ++i) sc[i] = 0.f;
      __builtin_amdgcn_s_setprio(1);
#pragma unroll
      for (int m = 0; m < 8; ++m) {
        bf16x8 kf = *(const bf16x8*)&SMEM[buf][((kh * 8 + m) * 512) + lane * 8];
        sc = mfma32(kf, bq[m], sc);
      }
      __builtin_amdgcn_s_setprio(0);

      // per-lane softmax: all 16 scores belong to q = l31
      float pf[16];
      int kb = k0 + kh * 32 + h5 * 4;
      bool nomask = (k0 + kh * 32 + 31) <= qw;   // wave-uniform
      if (nomask) {
#pragma unroll
        for (int reg = 0; reg < 16; ++reg) {
          float v = __builtin_amdgcn_fmed3f(sc[reg] * c2, -clip2, clip2);
          float pc = __builtin_amdgcn_exp2f(v);
          rs += pc;
          pf[reg] = pc;
        }
      } else {
#pragma unroll
        for (int reg = 0; reg < 16; ++reg) {
          int key = kb + (reg & 3) + 8 * (reg >> 2);
          float v = __builtin_amdgcn_fmed3f(sc[reg] * c2, -clip2, clip2);
          float pc = __builtin_amdgcn_exp2f(v);
          pc = (key > qrow) ? 0.0f : pc;
          rs += pc;
          pf[reg] = pc;
        }
      }
      // pack P -> PV A-fragments
      u32 cv0 = cvtpk(pf[0], pf[1]), cv1 = cvtpk(pf[2], pf[3]);
      u32 cv2 = cvtpk(pf[4], pf[5]), cv3 = cvtpk(pf[6], pf[7]);
      u32 cv4 = cvtpk(pf[8], pf[9]), cv5 = cvtpk(pf[10], pf[11]);
      u32 cv6 = cvtpk(pf[12], pf[13]), cv7 = cvtpk(pf[14], pf[15]);
      u32x2 s0 = pswap(cv0, cv2);
      u32x2 s1 = pswap(cv1, cv3);
      u32x2 s2 = pswap(cv4, cv6);
      u32x2 s3 = pswap(cv5, cv7);
      u32x4 pa0u = {s0.x, s1.x, s0.y, s1.y};
      u32x4 pa1u = {s2.x, s3.x, s2.y, s3.y};
      bf16x8 pa0 = __builtin_bit_cast(bf16x8, pa0u);
      bf16x8 pa1 = __builtin_bit_cast(bf16x8, pa1u);
      __builtin_amdgcn_s_setprio(1);
      y0 = mfma32(pa0, vc[0], y0);
      y0 = mfma32(pa1, vc[4], y0);
      y1 = mfma32(pa0, vc[1], y1);
      y1 = mfma32(pa1, vc[5], y1);
      y2 = mfma32(pa0, vc[2], y2);
      y2 = mfma32(pa1, vc[6], y2);
      y3 = mfma32(pa0, vc[3], y3);
      y3 = mfma32(pa1, vc[7], y3);
      __builtin_amdgcn_s_setprio(0);
    };

    int NT = 2 * qblk + 2;   // even
    issue(0, 0);
    issue(64, 1);
    vload(vA, 0);
    __syncthreads();  // prologue: full drain once per segment
    for (int t = 0; t < NT; t += 2) {
      int k0 = t * 64;
      vload(vB, k0 + 64);                       // V(t+1): oldest vmem group
      if (t + 2 < NT) issue(k0 + 128, (t + 2) & 3);  // K-glls next
      if (t + 3 < NT) issue(k0 + 192, (t + 3) & 3);
      __builtin_amdgcn_sched_barrier(0);        // pin: glls issued before vA
      tilecomp(t & 3, k0, vA);
      if (t + 2 < NT) vload(vA, k0 + 128);      // V(t+2): newest vmem group
      __builtin_amdgcn_sched_barrier(0);        // pin: vA issued by here
      tilecomp((t + 1) & 3, k0 + 64, vB);       // vB use: compiler counted-wait
      // counted barrier: drain glls (cross-wave LDS visibility), keep vA(8)
      asm volatile("s_waitcnt vmcnt(8)" ::: "memory");
      __builtin_amdgcn_s_barrier();
      __builtin_amdgcn_sched_barrier(0);        // nothing crosses the barrier
    }

    // rs: combine the two h5 key-subsets (same q)
    rs += __shfl_xor(rs, 32, 64);

    // key-half combine through the dead K LDS: 16KB scratch per qr group
    float* scr = (float*)&SMEM[0][0] + qr * 4096;
    if (kh == 1) {
#pragma unroll
      for (int db = 0; db < 4; ++db) {
        const f32x16& yv = (db == 0) ? y0 : (db == 1) ? y1 : (db == 2) ? y2 : y3;
#pragma unroll
        for (int r4 = 0; r4 < 4; ++r4) {
          f32x4 ch = {yv[r4 * 4 + 0], yv[r4 * 4 + 1], yv[r4 * 4 + 2], yv[r4 * 4 + 3]};
          *(f32x4*)&scr[((db * 4 + r4) * 64 + lane) * 4] = ch;
        }
      }
      if (lane < 32) rsbuf[1][qr][lane] = rs;
    }
    __syncthreads();
    if (kh == 0) {
      float rs2 = rs + rsbuf[1][qr][l31];
      float inv = 1.0f / rs2;
      if (lane < 32) rsbuf[0][qr][lane] = inv;
#pragma unroll
      for (int db = 0; db < 4; ++db) {
        f32x16& yv = (db == 0) ? y0 : (db == 1) ? y1 : (db == 2) ? y2 : y3;
#pragma unroll
        for (int r4 = 0; r4 < 4; ++r4) {
          f32x4 ch = *(const f32x4*)&scr[((db * 4 + r4) * 64 + lane) * 4];
#pragma unroll
          for (int k = 0; k < 4; ++k) yv[r4 * 4 + k] += ch[k];
        }
      }
      u16* Yp = Yb + ((size_t)b * S_LEN + qw) * (NHEAD * DHEAD) + h * DHEAD;
#pragma unroll
      for (int db = 0; db < 4; ++db) {
        const f32x16& yv = (db == 0) ? y0 : (db == 1) ? y1 : (db == 2) ? y2 : y3;
#pragma unroll
        for (int reg = 0; reg < 16; ++reg) {
          int qp2 = (reg & 3) + 8 * (reg >> 2) + 4 * h5;
          float rv = rsbuf[0][qr][qp2];
          Yp[(size_t)qp2 * (NHEAD * DHEAD) + db * 32 + l31] = f2b(yv[reg] * rv);
        }
      }
    }
    __syncthreads();  // scratch + rsbuf reads done before next segment stages
  };

  runSeg(31 - qpj);   // long segment first
  runSeg(qpj);        // complementary short: 68 tiles for every block, flat
}

// ---------------- output projection: 4 waves/block ----------------
__global__ __launch_bounds__(256) void k_oproj(const u16* __restrict__ Yb,
                                               const u16* __restrict__ WoB,
                                               float* __restrict__ out) {
  int wid = threadIdx.x >> 6;
  int lane = threadIdx.x & 63;
  int mb = (blockIdx.x * 4 + wid) * 32 + blockIdx.y * 16;
  int nb = blockIdx.z * 64;
  int row16 = lane & 15, kgrp = lane >> 4;
  f32x4 acc[4];
#pragma unroll
  for (int nc = 0; nc < 4; ++nc) acc[nc] = zero4();
#pragma unroll 4
  for (int kc = 0; kc < 32; ++kc) {
    bf16x8 a0 = *(const bf16x8*)(Yb + (size_t)(mb + row16) * 1024 + kc * 32 + kgrp * 8);
#pragma unroll
    for (int nc = 0; nc < 4; ++nc) {
      bf16x8 bw =
          *(const bf16x8*)(WoB + (size_t)(nb + nc * 16 + row16) * 1024 + kc * 32 + kgrp * 8);
      acc[nc] = mfma16(a0, bw, acc[nc]);
    }
  }
#pragma unroll
  for (int nc = 0; nc < 4; ++nc)
#pragma unroll
    for (int i = 0; i < 4; ++i)
      out[(size_t)(mb + kgrp * 4 + i) * DHEAD + nb + nc * 16 + row16] = acc[nc][i];
}

extern "C" void kernel_launch(void* const* d_in, const int* in_sizes, int n_in,
                              void* d_out, int out_size, void* d_ws, size_t ws_size,
                              hipStream_t stream) {
  const float* x = (const float*)d_in[0];
  const float* Wq = (const float*)d_in[1];
  const float* Wk = (const float*)d_in[2];
  const float* Wo = (const float*)d_in[3];
  float* out = (float*)d_out;

  char* ws = (char*)d_ws;
  size_t off = 0;
  auto alloc = [&](size_t bytes) -> void* {
    void* p = ws + off;
    off += (bytes + 255) & ~(size_t)255;
    return p;
  };
  const size_t nx = (size_t)NBATCH * S_LEN * DHEAD;
  const size_t nqk = (size_t)NBATCH * NHEAD * S_LEN * DHEAD;
  u16* xb = (u16*)alloc(nx * 2);
  u16* VbF = (u16*)alloc(nx * 2);
  u16* Wqt = (u16*)alloc((size_t)NHEAD * DHEAD * DHEAD * 2);
  u16* Wkt = (u16*)alloc((size_t)NHEAD * DHEAD * DHEAD * 2);
  u16* WoB = (u16*)alloc((size_t)DHEAD * NHEAD * DHEAD * 2);
  u16* Qb = (u16*)alloc(nqk * 2);
  u16* KbF = (u16*)alloc(nqk * 2);
  u16* Yb = (u16*)alloc(nqk * 2);
  (void)ws_size;

  k_conv_x<<<dim3(nx / 256), dim3(256), 0, stream>>>(x, xb, VbF);
  k_conv_w<<<dim3(131072 / 256), dim3(256), 0, stream>>>(Wq, Wk, Wo, Wqt, Wkt, WoB);
  k_proj<<<dim3(S_LEN / 32 / 4, NHEAD, 2 * NBATCH), dim3(256), 0, stream>>>(xb, Wqt, Wkt, Qb, KbF);
  k_attn<<<dim3(256), dim3(512), 0, stream>>>(Qb, KbF, VbF, Yb);
  k_oproj<<<dim3((NBATCH * S_LEN) / 32 / 4, 2, 2), dim3(256), 0, stream>>>(Yb, WoB, out);
}

// Round 19
// 142.046 us; speedup vs baseline: 1.3822x; 1.0158x over previous
//
#include <hip/hip_runtime.h>
#include <hip/hip_bf16.h>

typedef unsigned short u16;
typedef unsigned int u32;
typedef __attribute__((ext_vector_type(8))) short bf16x8;
typedef __attribute__((ext_vector_type(4))) float f32x4;
typedef __attribute__((ext_vector_type(16))) float f32x16;
typedef __attribute__((ext_vector_type(2))) unsigned int u32x2;
typedef __attribute__((ext_vector_type(4))) unsigned int u32x4;

#define S_LEN 4096
#define DHEAD 128
#define NHEAD 8
#define NBATCH 2

__device__ __forceinline__ u16 f2b(float f) {
  __hip_bfloat16 h = __float2bfloat16(f);
  return *(u16*)&h;
}

__device__ __forceinline__ f32x4 mfma16(bf16x8 a, bf16x8 b, f32x4 c) {
  return __builtin_amdgcn_mfma_f32_16x16x32_bf16(a, b, c, 0, 0, 0);
}
__device__ __forceinline__ f32x16 mfma32(bf16x8 a, bf16x8 b, f32x16 c) {
  return __builtin_amdgcn_mfma_f32_32x32x16_bf16(a, b, c, 0, 0, 0);
}

__device__ __forceinline__ f32x4 zero4() { f32x4 z = {0.f, 0.f, 0.f, 0.f}; return z; }

__device__ __forceinline__ u32 cvtpk(float lo, float hi) {
  u32 r;
  asm("v_cvt_pk_bf16_f32 %0, %1, %2" : "=v"(r) : "v"(lo), "v"(hi));
  return r;
}
__device__ __forceinline__ u32x2 pswap(u32 a, u32 b) {
  return __builtin_amdgcn_permlane32_swap(a, b, false, false);
}

// pack C-layout regs (offset (r&3)+8*(r>>2)+4*h5 on rows, col=lane&31) into two
// A-operand frags: pa0 = slice 0..15 (h5*8+j), pa1 = slice 16..31. Verified by
// the attn P->PV path (refcheck) since r15.
__device__ __forceinline__ void packA(const float* pf, bf16x8& pa0, bf16x8& pa1) {
  u32 cv0 = cvtpk(pf[0], pf[1]), cv1 = cvtpk(pf[2], pf[3]);
  u32 cv2 = cvtpk(pf[4], pf[5]), cv3 = cvtpk(pf[6], pf[7]);
  u32 cv4 = cvtpk(pf[8], pf[9]), cv5 = cvtpk(pf[10], pf[11]);
  u32 cv6 = cvtpk(pf[12], pf[13]), cv7 = cvtpk(pf[14], pf[15]);
  u32x2 s0 = pswap(cv0, cv2), s1 = pswap(cv1, cv3);
  u32x2 s2 = pswap(cv4, cv6), s3 = pswap(cv5, cv7);
  u32x4 a0 = {s0.x, s1.x, s0.y, s1.y};
  u32x4 a1 = {s2.x, s3.x, s2.y, s3.y};
  pa0 = __builtin_bit_cast(bf16x8, a0);
  pa1 = __builtin_bit_cast(bf16x8, a1);
}

// async global->LDS, 16B/lane; LDS dest = wave-uniform base + lane*16
__device__ __forceinline__ void gll16(const u16* g, u16* l) {
  __builtin_amdgcn_global_load_lds(
      (const __attribute__((address_space(1))) u32*)g,
      (__attribute__((address_space(3))) u32*)l, 16, 0, 0);
}

// ---------------- V convert: coalesced frag-centric fill ----------------
// thread = one VbF lane-slot (16B): writes contiguous, reads 8 f32 coalesced
// across lanes (d consecutive per 32-lane half).
__global__ void k_conv_x(const float* __restrict__ x, u16* __restrict__ VbF) {
  int idx = blockIdx.x * blockDim.x + threadIdx.x;  // 0..131071
  int b = idx >> 16;
  int t64 = (idx >> 10) & 63;
  int g = (idx >> 6) & 15;
  int l = idx & 63;
  int kh = g >> 3, m2 = (g >> 2) & 1, db = g & 3;
  int keyb = t64 * 64 + kh * 32 + m2 * 16 + (l >> 5) * 8;
  int d = db * 32 + (l & 31);
  const float* xp = x + ((size_t)b * S_LEN + keyb) * DHEAD + d;
  u16 o[8];
#pragma unroll
  for (int j = 0; j < 8; ++j) o[j] = f2b(xp[(size_t)j * DHEAD]);
  *(bf16x8*)(VbF + (size_t)idx * 8) = *(const bf16x8*)o;
}

__global__ void k_conv_w(const float* __restrict__ Wq, const float* __restrict__ Wk,
                         const float* __restrict__ Wo, u16* __restrict__ Wqt,
                         u16* __restrict__ Wkt, u16* __restrict__ WoB) {
  int idx = blockIdx.x * blockDim.x + threadIdx.x;
  int h = idx >> 14;
  int d = (idx >> 7) & 127;
  int e = idx & 127;
  int t = (h << 14) + (e << 7) + d;
  Wqt[t] = f2b(Wq[idx]);
  Wkt[t] = f2b(Wk[idx]);
  WoB[idx] = f2b(Wo[idx]);
}

// ---------------- Q/K projection: fragment-native outputs ----------------
// Per wave: 32 rows (keys/queries) x 128 e. Swapped mfma32: C[e][key] with
// key on lane&31 -> packA -> A-operand frags -> COALESCED 16B/lane stores.
// QbF: [((bh*128+qt)*8 + m)*512 + l*8]   (m = e>>4)
// KbF: [((bh*64+t64)*16 + kh*8 + m)*512 + l*8]  (same layout attn stages from)
__global__ __launch_bounds__(256) void k_proj(const float* __restrict__ x,
                                              const u16* __restrict__ Wqt,
                                              const u16* __restrict__ Wkt,
                                              u16* __restrict__ QbF, u16* __restrict__ KbF) {
  int wid = threadIdx.x >> 6;
  int lane = threadIdx.x & 63;
  int qt = blockIdx.x * 4 + wid;     // 0..127 (32-row tile)
  int h = blockIdx.y, z = blockIdx.z;
  int b = z >> 1, w = z & 1;
  int bh = b * NHEAD + h;
  int l31 = lane & 31, h5 = lane >> 5;
  int sb = qt * 32;

  // B-frags from f32 x: lane holds row sb+l31, d-slice dk*16+h5*8 .. +7
  const float* xp = x + ((size_t)b * S_LEN + sb + l31) * DHEAD;
  bf16x8 bx[8];
#pragma unroll
  for (int dk = 0; dk < 8; ++dk) {
    f32x4 lo = *(const f32x4*)(xp + dk * 16 + h5 * 8);
    f32x4 hi = *(const f32x4*)(xp + dk * 16 + h5 * 8 + 4);
    u32x4 pk = {cvtpk(lo[0], lo[1]), cvtpk(lo[2], lo[3]),
                cvtpk(hi[0], hi[1]), cvtpk(hi[2], hi[3])};
    bx[dk] = __builtin_bit_cast(bf16x8, pk);
  }

  const u16* Wt = (w == 0 ? Wqt : Wkt) + (size_t)h * DHEAD * DHEAD;
  u16* Out = (w == 0 ? QbF : KbF);
  size_t obase = (w == 0)
                     ? ((size_t)(bh * 128 + qt) * 8) * 512
                     : (((size_t)bh * 64 + (qt >> 1)) * 16 + (qt & 1) * 8) * 512;

#pragma unroll
  for (int eb = 0; eb < 4; ++eb) {
    f32x16 sc;
#pragma unroll
    for (int i = 0; i < 16; ++i) sc[i] = 0.f;
#pragma unroll
    for (int dk = 0; dk < 8; ++dk) {
      // A-frag: rows e=eb*32+l31, k-slice d=dk*16+h5*8 .. +7
      bf16x8 aw = *(const bf16x8*)(Wt + (size_t)(eb * 32 + l31) * DHEAD + dk * 16 + h5 * 8);
      sc = mfma32(aw, bx[dk], sc);
    }
    float pf[16];
#pragma unroll
    for (int i = 0; i < 16; ++i) pf[i] = sc[i];
    bf16x8 pa0, pa1;
    packA(pf, pa0, pa1);
    *(bf16x8*)(Out + obase + (size_t)(eb * 2 + 0) * 512 + lane * 8) = pa0;
    *(bf16x8*)(Out + obase + (size_t)(eb * 2 + 1) * 512 + lane * 8) = pa1;
  }
}

// ---------------- causal flash attention (r18 structure, QbF input) ----------
__global__ __launch_bounds__(512) void k_attn(const u16* __restrict__ QbF,
                                              const u16* __restrict__ KbF,
                                              const u16* __restrict__ VbF,
                                              u16* __restrict__ Yb) {
  int p = blockIdx.x;                      // 0..255
  int xcd = p & 7;
  int j2 = p >> 3;                         // 0..31
  int bh = xcd + (j2 >= 16 ? 8 : 0);       // 0..15 (same (b,h) per XCD)
  int qpj = j2 & 15;
  int b = bh >> 3, h = bh & 7;

  int tid = threadIdx.x;
  int wid = tid >> 6;                      // 0..7
  int lane = tid & 63;
  int qr = wid >> 1;                       // 0..3 (32 q-rows each)
  int kh = wid & 1;                        // key half of 64-key tile
  int l31 = lane & 31, h5 = lane >> 5;

  __shared__ __align__(16) u16 SMEM[4][8192];   // 64 KB: K 4-deep / combine scr
  __shared__ float rsbuf[2][4][32];             // 1 KB

  const u16* Kbase = KbF + (size_t)bh * 64 * 16 * 512;
  const u16* Vbase = VbF + (size_t)b * 64 * 16 * 512;

  auto issue = [&](int k0, int buf) {
    const u16* Ks = Kbase + (size_t)(k0 >> 6) * 16 * 512;
#pragma unroll
    for (int fi = 0; fi < 2; ++fi) {
      int f = wid * 2 + fi;
      gll16(Ks + f * 512 + lane * 8, &SMEM[buf][f * 512]);
    }
  };
  auto vload = [&](bf16x8 (&dst)[8], int k0) {
    const u16* Vs = Vbase + ((size_t)(k0 >> 6) * 16 + kh * 8) * 512 + lane * 8;
#pragma unroll
    for (int g = 0; g < 8; ++g) dst[g] = *(const bf16x8*)(Vs + g * 512);
  };

  const float c2 = 0.12754274816295166f;    // (1/sqrt(128)) * log2(e)
  const float clip2 = 14.426950408889634f;  // 10 * log2(e)

  auto runSeg = [&](int qblk) {
    int qb0 = qblk * 128;
    int qw = qb0 + qr * 32;
    int qrow = qw + l31;                   // this lane's q-row
    // bq from fragment-ordered QbF: contiguous 16B/lane
    const u16* Qp = QbF + ((size_t)(bh * 128 + (qw >> 5)) * 8) * 512;

    bf16x8 bq[8];
#pragma unroll
    for (int m = 0; m < 8; ++m)
      bq[m] = *(const bf16x8*)(Qp + (size_t)m * 512 + lane * 8);

    f32x16 y0, y1, y2, y3;
#pragma unroll
    for (int i = 0; i < 16; ++i) { y0[i] = 0.f; y1[i] = 0.f; y2[i] = 0.f; y3[i] = 0.f; }
    float rs = 0.f;

    bf16x8 vA[8], vB[8];

    auto tilecomp = [&](int buf, int k0, bf16x8 (&vc)[8]) {
      f32x16 sc;
#pragma unroll
      for (int i = 0; i < 16; ++i) sc[i] = 0.f;
      __builtin_amdgcn_s_setprio(1);
#pragma unroll
      for (int m = 0; m < 8; ++m) {
        bf16x8 kf = *(const bf16x8*)&SMEM[buf][((kh * 8 + m) * 512) + lane * 8];
        sc = mfma32(kf, bq[m], sc);
      }
      __builtin_amdgcn_s_setprio(0);

      float pf[16];
      int kb = k0 + kh * 32 + h5 * 4;
      bool nomask = (k0 + kh * 32 + 31) <= qw;   // wave-uniform
      if (nomask) {
#pragma unroll
        for (int reg = 0; reg < 16; ++reg) {
          float v = __builtin_amdgcn_fmed3f(sc[reg] * c2, -clip2, clip2);
          float pc = __builtin_amdgcn_exp2f(v);
          rs += pc;
          pf[reg] = pc;
        }
      } else {
#pragma unroll
        for (int reg = 0; reg < 16; ++reg) {
          int key = kb + (reg & 3) + 8 * (reg >> 2);
          float v = __builtin_amdgcn_fmed3f(sc[reg] * c2, -clip2, clip2);
          float pc = __builtin_amdgcn_exp2f(v);
          pc = (key > qrow) ? 0.0f : pc;
          rs += pc;
          pf[reg] = pc;
        }
      }
      bf16x8 pa0, pa1;
      packA(pf, pa0, pa1);
      __builtin_amdgcn_s_setprio(1);
      y0 = mfma32(pa0, vc[0], y0);
      y0 = mfma32(pa1, vc[4], y0);
      y1 = mfma32(pa0, vc[1], y1);
      y1 = mfma32(pa1, vc[5], y1);
      y2 = mfma32(pa0, vc[2], y2);
      y2 = mfma32(pa1, vc[6], y2);
      y3 = mfma32(pa0, vc[3], y3);
      y3 = mfma32(pa1, vc[7], y3);
      __builtin_amdgcn_s_setprio(0);
    };

    int NT = 2 * qblk + 2;   // even
    issue(0, 0);
    issue(64, 1);
    vload(vA, 0);
    __syncthreads();  // prologue: full drain once per segment
    for (int t = 0; t < NT; t += 2) {
      int k0 = t * 64;
      vload(vB, k0 + 64);                       // V(t+1): oldest vmem group
      if (t + 2 < NT) issue(k0 + 128, (t + 2) & 3);
      if (t + 3 < NT) issue(k0 + 192, (t + 3) & 3);
      __builtin_amdgcn_sched_barrier(0);
      tilecomp(t & 3, k0, vA);
      if (t + 2 < NT) vload(vA, k0 + 128);
      __builtin_amdgcn_sched_barrier(0);
      tilecomp((t + 1) & 3, k0 + 64, vB);
      asm volatile("s_waitcnt vmcnt(8)" ::: "memory");  // keep vA in flight
      __builtin_amdgcn_s_barrier();
      __builtin_amdgcn_sched_barrier(0);
    }

    rs += __shfl_xor(rs, 32, 64);

    float* scr = (float*)&SMEM[0][0] + qr * 4096;
    if (kh == 1) {
#pragma unroll
      for (int db = 0; db < 4; ++db) {
        const f32x16& yv = (db == 0) ? y0 : (db == 1) ? y1 : (db == 2) ? y2 : y3;
#pragma unroll
        for (int r4 = 0; r4 < 4; ++r4) {
          f32x4 ch = {yv[r4 * 4 + 0], yv[r4 * 4 + 1], yv[r4 * 4 + 2], yv[r4 * 4 + 3]};
          *(f32x4*)&scr[((db * 4 + r4) * 64 + lane) * 4] = ch;
        }
      }
      if (lane < 32) rsbuf[1][qr][lane] = rs;
    }
    __syncthreads();
    if (kh == 0) {
      float rs2 = rs + rsbuf[1][qr][l31];
      float inv = 1.0f / rs2;
      if (lane < 32) rsbuf[0][qr][lane] = inv;
#pragma unroll
      for (int db = 0; db < 4; ++db) {
        f32x16& yv = (db == 0) ? y0 : (db == 1) ? y1 : (db == 2) ? y2 : y3;
#pragma unroll
        for (int r4 = 0; r4 < 4; ++r4) {
          f32x4 ch = *(const f32x4*)&scr[((db * 4 + r4) * 64 + lane) * 4];
#pragma unroll
          for (int k = 0; k < 4; ++k) yv[r4 * 4 + k] += ch[k];
        }
      }
      u16* Yp = Yb + ((size_t)b * S_LEN + qw) * (NHEAD * DHEAD) + h * DHEAD;
#pragma unroll
      for (int db = 0; db < 4; ++db) {
        const f32x16& yv = (db == 0) ? y0 : (db == 1) ? y1 : (db == 2) ? y2 : y3;
#pragma unroll
        for (int reg = 0; reg < 16; ++reg) {
          int qp2 = (reg & 3) + 8 * (reg >> 2) + 4 * h5;
          float rv = rsbuf[0][qr][qp2];
          Yp[(size_t)qp2 * (NHEAD * DHEAD) + db * 32 + l31] = f2b(yv[reg] * rv);
        }
      }
    }
    __syncthreads();
  };

  runSeg(31 - qpj);
  runSeg(qpj);
}

// ---------------- output projection: 4 waves/block ----------------
__global__ __launch_bounds__(256) void k_oproj(const u16* __restrict__ Yb,
                                               const u16* __restrict__ WoB,
                                               float* __restrict__ out) {
  int wid = threadIdx.x >> 6;
  int lane = threadIdx.x & 63;
  int mb = (blockIdx.x * 4 + wid) * 32 + blockIdx.y * 16;
  int nb = blockIdx.z * 64;
  int row16 = lane & 15, kgrp = lane >> 4;
  f32x4 acc[4];
#pragma unroll
  for (int nc = 0; nc < 4; ++nc) acc[nc] = zero4();
#pragma unroll 4
  for (int kc = 0; kc < 32; ++kc) {
    bf16x8 a0 = *(const bf16x8*)(Yb + (size_t)(mb + row16) * 1024 + kc * 32 + kgrp * 8);
#pragma unroll
    for (int nc = 0; nc < 4; ++nc) {
      bf16x8 bw =
          *(const bf16x8*)(WoB + (size_t)(nb + nc * 16 + row16) * 1024 + kc * 32 + kgrp * 8);
      acc[nc] = mfma16(a0, bw, acc[nc]);
    }
  }
#pragma unroll
  for (int nc = 0; nc < 4; ++nc)
#pragma unroll
    for (int i = 0; i < 4; ++i)
      out[(size_t)(mb + kgrp * 4 + i) * DHEAD + nb + nc * 16 + row16] = acc[nc][i];
}

extern "C" void kernel_launch(void* const* d_in, const int* in_sizes, int n_in,
                              void* d_out, int out_size, void* d_ws, size_t ws_size,
                              hipStream_t stream) {
  const float* x = (const float*)d_in[0];
  const float* Wq = (const float*)d_in[1];
  const float* Wk = (const float*)d_in[2];
  const float* Wo = (const float*)d_in[3];
  float* out = (float*)d_out;

  char* ws = (char*)d_ws;
  size_t off = 0;
  auto alloc = [&](size_t bytes) -> void* {
    void* p = ws + off;
    off += (bytes + 255) & ~(size_t)255;
    return p;
  };
  const size_t nx = (size_t)NBATCH * S_LEN * DHEAD;
  const size_t nqk = (size_t)NBATCH * NHEAD * S_LEN * DHEAD;
  u16* VbF = (u16*)alloc(nx * 2);
  u16* Wqt = (u16*)alloc((size_t)NHEAD * DHEAD * DHEAD * 2);
  u16* Wkt = (u16*)alloc((size_t)NHEAD * DHEAD * DHEAD * 2);
  u16* WoB = (u16*)alloc((size_t)DHEAD * NHEAD * DHEAD * 2);
  u16* QbF = (u16*)alloc(nqk * 2);
  u16* KbF = (u16*)alloc(nqk * 2);
  u16* Yb = (u16*)alloc(nqk * 2);
  (void)ws_size;

  k_conv_x<<<dim3(512), dim3(256), 0, stream>>>(x, VbF);
  k_conv_w<<<dim3(131072 / 256), dim3(256), 0, stream>>>(Wq, Wk, Wo, Wqt, Wkt, WoB);
  k_proj<<<dim3(S_LEN / 32 / 4, NHEAD, 2 * NBATCH), dim3(256), 0, stream>>>(x, Wqt, Wkt, QbF, KbF);
  k_attn<<<dim3(256), dim3(512), 0, stream>>>(QbF, KbF, VbF, Yb);
  k_oproj<<<dim3((NBATCH * S_LEN) / 32 / 4, 2, 2), dim3(256), 0, stream>>>(Yb, WoB, out);
}